// Round 1
// baseline (942.871 us; speedup 1.0000x reference)
//
#include <hip/hip_runtime.h>
#include <hip/hip_bf16.h>

// Problem constants (validated against in_sizes at launch)
#define IN_DIM   256
#define NUM_HEAD 8
#define OUT_DIM  32
#define D_TOT    256          // NUM_HEAD*OUT_DIM
#define SCALE    0.17677669529663687f   // 1/sqrt(32)
#define EPS      1e-9f

// ---------------------------------------------------------------------------
// Fused QKV GEMM (fp32): out = h @ W + b, one of q/k/v selected by blockIdx.z
// Tile: BM=64, BN=64, BK=32; 256 threads; 4x4 acc per thread.
// ---------------------------------------------------------------------------
#define GM_BM 64
#define GM_BN 64
#define GM_BK 32

__global__ __launch_bounds__(256) void qkv_gemm(
    const float* __restrict__ h,
    const float* __restrict__ Wq, const float* __restrict__ bq,
    const float* __restrict__ Wk, const float* __restrict__ bk,
    const float* __restrict__ Wv, const float* __restrict__ bv,
    float* __restrict__ qf, float* __restrict__ kf, float* __restrict__ vf,
    int M)
{
    const float* W; const float* bias; float* out;
    if (blockIdx.z == 0)      { W = Wq; bias = bq; out = qf; }
    else if (blockIdx.z == 1) { W = Wk; bias = bk; out = kf; }
    else                      { W = Wv; bias = bv; out = vf; }

    __shared__ float At[GM_BK][68];   // A transposed [k][row], pad 64->68 (16B-aligned rows, no bank conflict)
    __shared__ float Bs[GM_BK][64];   // B [k][col]

    const int tid = threadIdx.x;
    const int m0  = blockIdx.x * GM_BM;
    const int n0  = blockIdx.y * GM_BN;
    const int tx  = tid & 15;         // col group
    const int ty  = tid >> 4;         // row group

    float acc[4][4] = {};

    for (int k0 = 0; k0 < IN_DIM; k0 += GM_BK) {
        // Stage A: 64 rows x 32 k  (512 float4 loads, 2 per thread)
        #pragma unroll
        for (int ld = 0; ld < 2; ++ld) {
            int v   = tid + ld * 256;      // 0..511
            int r   = v >> 3;              // row within tile
            int kk4 = v & 7;               // which group of 4 k
            int row = m0 + r;
            float4 a;
            if (row < M) a = *(const float4*)&h[(size_t)row * IN_DIM + k0 + kk4 * 4];
            else         a = make_float4(0.f, 0.f, 0.f, 0.f);
            At[kk4 * 4 + 0][r] = a.x;
            At[kk4 * 4 + 1][r] = a.y;
            At[kk4 * 4 + 2][r] = a.z;
            At[kk4 * 4 + 3][r] = a.w;
        }
        // Stage B: 32 k x 64 cols
        #pragma unroll
        for (int ld = 0; ld < 2; ++ld) {
            int v  = tid + ld * 256;
            int c4 = v & 15;
            int kk = v >> 4;
            *(float4*)&Bs[kk][c4 * 4] =
                *(const float4*)&W[(size_t)(k0 + kk) * D_TOT + n0 + c4 * 4];
        }
        __syncthreads();

        #pragma unroll
        for (int kk = 0; kk < GM_BK; ++kk) {
            float4 a = *(const float4*)&At[kk][ty * 4];
            float4 b = *(const float4*)&Bs[kk][tx * 4];
            acc[0][0] += a.x * b.x; acc[0][1] += a.x * b.y; acc[0][2] += a.x * b.z; acc[0][3] += a.x * b.w;
            acc[1][0] += a.y * b.x; acc[1][1] += a.y * b.y; acc[1][2] += a.y * b.z; acc[1][3] += a.y * b.w;
            acc[2][0] += a.z * b.x; acc[2][1] += a.z * b.y; acc[2][2] += a.z * b.z; acc[2][3] += a.z * b.w;
            acc[3][0] += a.w * b.x; acc[3][1] += a.w * b.y; acc[3][2] += a.w * b.z; acc[3][3] += a.w * b.w;
        }
        __syncthreads();
    }

    float4 bb = *(const float4*)&bias[n0 + tx * 4];
    #pragma unroll
    for (int i = 0; i < 4; ++i) {
        int row = m0 + ty * 4 + i;
        if (row < M) {
            float4 o;
            o.x = acc[i][0] + bb.x;
            o.y = acc[i][1] + bb.y;
            o.z = acc[i][2] + bb.z;
            o.w = acc[i][3] + bb.w;
            *(float4*)&out[(size_t)row * D_TOT + n0 + tx * 4] = o;
        }
    }
}

// ---------------------------------------------------------------------------
// CSR build: histogram, scan, scatter
// ---------------------------------------------------------------------------
__global__ void hist_kernel(const int* __restrict__ dst, int* __restrict__ counts, int E)
{
    int i = blockIdx.x * blockDim.x + threadIdx.x;
    if (i < E) atomicAdd(&counts[dst[i]], 1);
}

__global__ __launch_bounds__(1024) void scan_kernel(
    const int* __restrict__ counts, int* __restrict__ offs,
    int* __restrict__ cursor, int n)
{
    __shared__ int wsum[16];
    __shared__ int carry_s;
    const int tid  = threadIdx.x;
    const int lane = tid & 63;
    const int wid  = tid >> 6;
    if (tid == 0) carry_s = 0;
    __syncthreads();

    for (int base = 0; base < n; base += 1024) {
        int i = base + tid;
        int x = (i < n) ? counts[i] : 0;
        int v = x;
        #pragma unroll
        for (int off = 1; off < 64; off <<= 1) {
            int t = __shfl_up(v, off);
            if (lane >= off) v += t;
        }
        if (lane == 63) wsum[wid] = v;
        __syncthreads();
        if (wid == 0) {
            int wv = (lane < 16) ? wsum[lane] : 0;
            #pragma unroll
            for (int off = 1; off < 16; off <<= 1) {
                int t = __shfl_up(wv, off);
                if (lane >= off) wv += t;
            }
            if (lane < 16) wsum[lane] = wv;
        }
        __syncthreads();
        int wbase = (wid > 0) ? wsum[wid - 1] : 0;
        int incl  = wbase + v;
        int excl  = incl - x;
        int carry = carry_s;
        if (i < n) { int o = carry + excl; offs[i] = o; cursor[i] = o; }
        __syncthreads();
        if (tid == 1023) carry_s = carry + incl;   // block total
        __syncthreads();
    }
    if (threadIdx.x == 0) offs[n] = carry_s;
}

__global__ void scatter_kernel(const int* __restrict__ src, const int* __restrict__ dst,
                               int* __restrict__ cursor, int* __restrict__ csr, int E)
{
    int i = blockIdx.x * blockDim.x + threadIdx.x;
    if (i < E) {
        int p = atomicAdd(&cursor[dst[i]], 1);
        csr[p] = src[i];
    }
}

// ---------------------------------------------------------------------------
// Attention aggregation: one 64-lane wave per destination node.
// lane l owns 4 contiguous channels (head = l/8); dot via 3x shfl_xor in
// 8-lane head groups; accumulate score*v in registers; one float4 store.
// ---------------------------------------------------------------------------
__global__ __launch_bounds__(256) void attn_kernel(
    const float* __restrict__ qf, const float* __restrict__ kf, const float* __restrict__ vf,
    const int* __restrict__ offs, const int* __restrict__ csr,
    float* __restrict__ out, int n)
{
    int wave = (int)((blockIdx.x * (size_t)blockDim.x + threadIdx.x) >> 6);
    if (wave >= n) return;
    const int lane = threadIdx.x & 63;
    const int j0   = lane * 4;

    const float4 qv = *(const float4*)&qf[(size_t)wave * D_TOT + j0];
    float acc0 = 0.f, acc1 = 0.f, acc2 = 0.f, acc3 = 0.f, z = 0.f;

    const int pend = offs[wave + 1];
    for (int p = offs[wave]; p < pend; ++p) {
        int s = csr[p];
        float4 kv = *(const float4*)&kf[(size_t)s * D_TOT + j0];
        float4 vv = *(const float4*)&vf[(size_t)s * D_TOT + j0];
        float part = kv.x * qv.x + kv.y * qv.y + kv.z * qv.z + kv.w * qv.w;
        part += __shfl_xor(part, 1);
        part += __shfl_xor(part, 2);
        part += __shfl_xor(part, 4);
        float sc = __expf(part * SCALE);
        acc0 += sc * vv.x;
        acc1 += sc * vv.y;
        acc2 += sc * vv.z;
        acc3 += sc * vv.w;
        z += sc;
    }
    float inv = 1.0f / (z + EPS);
    float4 o = make_float4(acc0 * inv, acc1 * inv, acc2 * inv, acc3 * inv);
    *(float4*)&out[(size_t)wave * D_TOT + j0] = o;
}

// ---------------------------------------------------------------------------
extern "C" void kernel_launch(void* const* d_in, const int* in_sizes, int n_in,
                              void* d_out, int out_size, void* d_ws, size_t ws_size,
                              hipStream_t stream)
{
    const float* h   = (const float*)d_in[0];
    const int*   src = (const int*)  d_in[1];
    const int*   dst = (const int*)  d_in[2];
    const float* Wq  = (const float*)d_in[3];
    const float* bq  = (const float*)d_in[4];
    const float* Wk  = (const float*)d_in[5];
    const float* bk  = (const float*)d_in[6];
    const float* Wv  = (const float*)d_in[7];
    const float* bv  = (const float*)d_in[8];
    float* out = (float*)d_out;

    const int N = in_sizes[0] / IN_DIM;
    const int E = in_sizes[1];

    // Workspace layout (fp32 q/k/v + CSR): ~160.6 MB
    float* qf     = (float*)d_ws;
    float* kf     = qf + (size_t)N * D_TOT;
    float* vf     = kf + (size_t)N * D_TOT;
    int*   offs   = (int*)(vf + (size_t)N * D_TOT);
    int*   cursor = offs + (N + 1);
    int*   counts = cursor + (N + 1);
    int*   csr    = counts + N;

    // 1) QKV projection
    {
        dim3 grid((N + GM_BM - 1) / GM_BM, D_TOT / GM_BN, 3);
        qkv_gemm<<<grid, 256, 0, stream>>>(h, Wq, bq, Wk, bk, Wv, bv, qf, kf, vf, N);
    }
    // 2) CSR by destination
    hipMemsetAsync(counts, 0, (size_t)N * sizeof(int), stream);
    {
        int blocks = (E + 255) / 256;
        hist_kernel<<<blocks, 256, 0, stream>>>(dst, counts, E);
        scan_kernel<<<1, 1024, 0, stream>>>(counts, offs, cursor, N);
        scatter_kernel<<<blocks, 256, 0, stream>>>(src, dst, cursor, csr, E);
    }
    // 3) Per-node attention aggregation (1 wave per node)
    {
        int waves_per_block = 4;                     // 256 threads
        int blocks = (N + waves_per_block - 1) / waves_per_block;
        attn_kernel<<<blocks, 256, 0, stream>>>(qf, kf, vf, offs, csr, out, N);
    }
}

// Round 2
// 599.251 us; speedup vs baseline: 1.5734x; 1.5734x over previous
//
#include <hip/hip_runtime.h>
#include <hip/hip_bf16.h>

#define IN_DIM   256
#define NUM_HEAD 8
#define OUT_DIM  32
#define D_TOT    256
#define SCALE    0.17677669529663687f   // 1/sqrt(32)
#define EPS      1e-9f

typedef __attribute__((ext_vector_type(4))) float f32x4;
typedef __attribute__((ext_vector_type(8))) short short8;

__device__ inline ushort f2bf(float f) {
    uint u = __float_as_uint(f);
    uint r = (u + 0x7FFF + ((u >> 16) & 1)) >> 16;   // round-to-nearest-even
    return (ushort)r;
}
__device__ inline float bf2f(ushort u) {
    return __uint_as_float(((uint)u) << 16);
}

// ---------------------------------------------------------------------------
// fp32 -> bf16 conversion for h (vectorized, 4 elems/thread)
// ---------------------------------------------------------------------------
__global__ void conv_h_kernel(const float* __restrict__ h, ushort* __restrict__ hb, int n)
{
    int i = blockIdx.x * blockDim.x + threadIdx.x;
    int base = i * 4;
    if (base < n) {
        float4 f = *(const float4*)&h[base];
        ushort4 o;
        o.x = f2bf(f.x); o.y = f2bf(f.y); o.z = f2bf(f.z); o.w = f2bf(f.w);
        *(ushort4*)&hb[base] = o;
    }
}

// fp32 W [K=256][N=256] -> bf16 W^T [N][K] (tiny: 3 x 256KB reads)
__global__ void conv_wT_kernel(const float* __restrict__ W, ushort* __restrict__ WT)
{
    int i = blockIdx.x * blockDim.x + threadIdx.x;   // i = k*256 + n
    if (i < D_TOT * IN_DIM) {
        int k = i >> 8, n = i & 255;
        WT[n * IN_DIM + k] = f2bf(W[i]);
    }
}

// ---------------------------------------------------------------------------
// QKV GEMM, bf16 MFMA 16x16x32. Tile BM=128, BN=64, BK=32, 4 waves (2x2).
// A in LDS [128][40] (pad->80B stride: 20-bank stride, conflict-free-ish),
// B^T in LDS [64][40]. blockIdx.z selects q/k/v.
// ---------------------------------------------------------------------------
__global__ __launch_bounds__(256) void qkv_gemm_mfma(
    const ushort* __restrict__ hb,
    const ushort* __restrict__ WqT, const float* __restrict__ bq,
    const ushort* __restrict__ WkT, const float* __restrict__ bk,
    const ushort* __restrict__ WvT, const float* __restrict__ bv,
    ushort* __restrict__ qb, ushort* __restrict__ kb, ushort* __restrict__ vb,
    int M)
{
    const ushort* WT; const float* bias; ushort* out;
    if (blockIdx.z == 0)      { WT = WqT; bias = bq; out = qb; }
    else if (blockIdx.z == 1) { WT = WkT; bias = bk; out = kb; }
    else                      { WT = WvT; bias = bv; out = vb; }

    __shared__ ushort A_lds[128][40];
    __shared__ ushort B_lds[64][40];

    const int tid  = threadIdx.x;
    const int m0   = blockIdx.x * 128;
    const int n0   = blockIdx.y * 64;
    const int lane = tid & 63;
    const int wid  = tid >> 6;
    const int wr   = wid >> 1;        // wave row  (0..1) -> 64 rows each
    const int wc   = wid & 1;         // wave col  (0..1) -> 32 cols each
    const int l15  = lane & 15;
    const int l4   = lane >> 4;

    f32x4 acc[4][2] = {};

    for (int k0 = 0; k0 < IN_DIM; k0 += 32) {
        // Stage A: 128 rows x 32 k  (512 x 16B, 2 per thread)
        #pragma unroll
        for (int it = 0; it < 2; ++it) {
            int v = tid + it * 256;
            int r = v >> 2, seg = v & 3;
            int row = m0 + r;
            uint4 val = make_uint4(0u, 0u, 0u, 0u);
            if (row < M) val = *(const uint4*)&hb[(size_t)row * IN_DIM + k0 + seg * 8];
            *(uint4*)&A_lds[r][seg * 8] = val;
        }
        // Stage B^T: 64 cols x 32 k (256 x 16B, 1 per thread)
        {
            int r = tid >> 2, seg = tid & 3;
            *(uint4*)&B_lds[r][seg * 8] =
                *(const uint4*)&WT[(size_t)(n0 + r) * IN_DIM + k0 + seg * 8];
        }
        __syncthreads();

        short8 afr[4], bfr[2];
        #pragma unroll
        for (int mi = 0; mi < 4; ++mi)
            afr[mi] = *(const short8*)&A_lds[wr * 64 + mi * 16 + l15][l4 * 8];
        #pragma unroll
        for (int ni = 0; ni < 2; ++ni)
            bfr[ni] = *(const short8*)&B_lds[wc * 32 + ni * 16 + l15][l4 * 8];
        #pragma unroll
        for (int mi = 0; mi < 4; ++mi)
            #pragma unroll
            for (int ni = 0; ni < 2; ++ni)
                acc[mi][ni] = __builtin_amdgcn_mfma_f32_16x16x32_bf16(
                    afr[mi], bfr[ni], acc[mi][ni], 0, 0, 0);
        __syncthreads();
    }

    float bias_c[2];
    #pragma unroll
    for (int ni = 0; ni < 2; ++ni)
        bias_c[ni] = bias[n0 + wc * 32 + ni * 16 + l15];

    #pragma unroll
    for (int mi = 0; mi < 4; ++mi) {
        #pragma unroll
        for (int r = 0; r < 4; ++r) {
            int row_g = m0 + wr * 64 + mi * 16 + l4 * 4 + r;
            if (row_g < M) {
                #pragma unroll
                for (int ni = 0; ni < 2; ++ni) {
                    int col_g = n0 + wc * 32 + ni * 16 + l15;
                    out[(size_t)row_g * D_TOT + col_g] = f2bf(acc[mi][ni][r] + bias_c[ni]);
                }
            }
        }
    }
}

// ---------------------------------------------------------------------------
// CSR build: histogram, scan (8 elems/thread), scatter
// ---------------------------------------------------------------------------
__global__ void hist_kernel(const int* __restrict__ dst, int* __restrict__ counts, int E)
{
    int i = blockIdx.x * blockDim.x + threadIdx.x;
    if (i < E) atomicAdd(&counts[dst[i]], 1);
}

__global__ __launch_bounds__(1024) void scan_kernel(
    const int* __restrict__ counts, int* __restrict__ offs,
    int* __restrict__ cursor, int n)
{
    __shared__ int wsum[16];
    __shared__ int carry_s;
    const int tid  = threadIdx.x;
    const int lane = tid & 63;
    const int wid  = tid >> 6;
    if (tid == 0) carry_s = 0;
    __syncthreads();

    const int PER_ITER = 1024 * 8;
    for (int base = 0; base < n; base += PER_ITER) {
        int i0 = base + tid * 8;
        int x[8];
        if (i0 + 7 < n) {
            int4 a = *(const int4*)&counts[i0];
            int4 b = *(const int4*)&counts[i0 + 4];
            x[0]=a.x; x[1]=a.y; x[2]=a.z; x[3]=a.w;
            x[4]=b.x; x[5]=b.y; x[6]=b.z; x[7]=b.w;
        } else {
            #pragma unroll
            for (int j = 0; j < 8; ++j) { int i = i0 + j; x[j] = (i < n) ? counts[i] : 0; }
        }
        int tot = 0;
        #pragma unroll
        for (int j = 0; j < 8; ++j) { int t = x[j]; x[j] = tot; tot += t; }
        int v = tot;
        #pragma unroll
        for (int off = 1; off < 64; off <<= 1) { int t = __shfl_up(v, off); if (lane >= off) v += t; }
        if (lane == 63) wsum[wid] = v;
        __syncthreads();
        if (wid == 0) {
            int wv = (lane < 16) ? wsum[lane] : 0;
            #pragma unroll
            for (int off = 1; off < 16; off <<= 1) { int t = __shfl_up(wv, off); if (lane >= off) wv += t; }
            if (lane < 16) wsum[lane] = wv;
        }
        __syncthreads();
        int wbase    = (wid > 0) ? wsum[wid - 1] : 0;
        int thr_excl = wbase + v - tot;
        int carry    = carry_s;
        #pragma unroll
        for (int j = 0; j < 8; ++j) {
            int i = i0 + j;
            if (i < n) { int o = carry + thr_excl + x[j]; offs[i] = o; cursor[i] = o; }
        }
        __syncthreads();
        if (tid == 1023) carry_s = carry + wbase + v;   // + block total
        __syncthreads();
    }
    if (tid == 0) offs[n] = carry_s;
}

__global__ void scatter_kernel(const int* __restrict__ src, const int* __restrict__ dst,
                               int* __restrict__ cursor, int* __restrict__ csr, int E)
{
    int i = blockIdx.x * blockDim.x + threadIdx.x;
    if (i < E) {
        int p = atomicAdd(&cursor[dst[i]], 1);
        csr[p] = src[i];
    }
}

// ---------------------------------------------------------------------------
// Attention aggregation: one wave per destination node, bf16 q/k/v.
// lane l owns 4 channels (8B ushort4 loads -> 512B/row coalesced).
// ---------------------------------------------------------------------------
__global__ __launch_bounds__(256) void attn_kernel(
    const ushort* __restrict__ qb, const ushort* __restrict__ kb, const ushort* __restrict__ vb,
    const int* __restrict__ offs, const int* __restrict__ csr,
    float* __restrict__ out, int n)
{
    int wave = (int)((blockIdx.x * (size_t)blockDim.x + threadIdx.x) >> 6);
    if (wave >= n) return;
    const int lane = threadIdx.x & 63;
    const int j0   = lane * 4;

    ushort4 qu = *(const ushort4*)&qb[(size_t)wave * D_TOT + j0];
    float q0 = bf2f(qu.x), q1 = bf2f(qu.y), q2 = bf2f(qu.z), q3 = bf2f(qu.w);

    float acc0 = 0.f, acc1 = 0.f, acc2 = 0.f, acc3 = 0.f, z = 0.f;

    const int pend = offs[wave + 1];
    for (int p = offs[wave]; p < pend; ++p) {
        int s = csr[p];
        ushort4 ku = *(const ushort4*)&kb[(size_t)s * D_TOT + j0];
        ushort4 vu = *(const ushort4*)&vb[(size_t)s * D_TOT + j0];
        float part = bf2f(ku.x) * q0 + bf2f(ku.y) * q1 + bf2f(ku.z) * q2 + bf2f(ku.w) * q3;
        part += __shfl_xor(part, 1);
        part += __shfl_xor(part, 2);
        part += __shfl_xor(part, 4);
        float sc = __expf(part * SCALE);
        acc0 += sc * bf2f(vu.x);
        acc1 += sc * bf2f(vu.y);
        acc2 += sc * bf2f(vu.z);
        acc3 += sc * bf2f(vu.w);
        z += sc;
    }
    float inv = 1.0f / (z + EPS);
    float4 o = make_float4(acc0 * inv, acc1 * inv, acc2 * inv, acc3 * inv);
    *(float4*)&out[(size_t)wave * D_TOT + j0] = o;
}

// ---------------------------------------------------------------------------
extern "C" void kernel_launch(void* const* d_in, const int* in_sizes, int n_in,
                              void* d_out, int out_size, void* d_ws, size_t ws_size,
                              hipStream_t stream)
{
    const float* h   = (const float*)d_in[0];
    const int*   src = (const int*)  d_in[1];
    const int*   dst = (const int*)  d_in[2];
    const float* Wq  = (const float*)d_in[3];
    const float* bq  = (const float*)d_in[4];
    const float* Wk  = (const float*)d_in[5];
    const float* bk  = (const float*)d_in[6];
    const float* Wv  = (const float*)d_in[7];
    const float* bv  = (const float*)d_in[8];
    float* out = (float*)d_out;

    const int N = in_sizes[0] / IN_DIM;
    const int E = in_sizes[1];

    // Workspace layout (bf16 q/k/v/h + W^T + CSR): ~110 MB
    ushort* qb  = (ushort*)d_ws;
    ushort* kb  = qb + (size_t)N * D_TOT;
    ushort* vb  = kb + (size_t)N * D_TOT;
    ushort* hb  = vb + (size_t)N * D_TOT;
    ushort* WqT = hb + (size_t)N * IN_DIM;
    ushort* WkT = WqT + D_TOT * IN_DIM;
    ushort* WvT = WkT + D_TOT * IN_DIM;
    int* offs   = (int*)(WvT + D_TOT * IN_DIM);
    int* cursor = offs + (N + 8);      // padded to keep 16B alignment downstream
    int* counts = cursor + (N + 8);
    int* csr    = counts + N;

    // 1) Convert inputs to bf16 (h) / bf16-transposed (W)
    {
        int n = N * IN_DIM;
        conv_h_kernel<<<(n / 4 + 255) / 256, 256, 0, stream>>>(h, hb, n);
        int wn = D_TOT * IN_DIM;
        conv_wT_kernel<<<(wn + 255) / 256, 256, 0, stream>>>(Wq, WqT);
        conv_wT_kernel<<<(wn + 255) / 256, 256, 0, stream>>>(Wk, WkT);
        conv_wT_kernel<<<(wn + 255) / 256, 256, 0, stream>>>(Wv, WvT);
    }
    // 2) QKV projection (bf16 MFMA)
    {
        dim3 grid((N + 127) / 128, D_TOT / 64, 3);
        qkv_gemm_mfma<<<grid, 256, 0, stream>>>(hb, WqT, bq, WkT, bk, WvT, bv,
                                                qb, kb, vb, N);
    }
    // 3) CSR by destination
    hipMemsetAsync(counts, 0, (size_t)N * sizeof(int), stream);
    {
        int blocks = (E + 255) / 256;
        hist_kernel<<<blocks, 256, 0, stream>>>(dst, counts, E);
        scan_kernel<<<1, 1024, 0, stream>>>(counts, offs, cursor, N);
        scatter_kernel<<<blocks, 256, 0, stream>>>(src, dst, cursor, csr, E);
    }
    // 4) Per-node attention aggregation (1 wave per node)
    {
        int blocks = (N + 3) / 4;
        attn_kernel<<<blocks, 256, 0, stream>>>(qb, kb, vb, offs, csr, out, N);
    }
}

// Round 4
// 544.980 us; speedup vs baseline: 1.7301x; 1.0996x over previous
//
#include <hip/hip_runtime.h>
#include <hip/hip_bf16.h>

#define IN_DIM   256
#define NUM_HEAD 8
#define OUT_DIM  32
#define D_TOT    256
#define SCALE    0.17677669529663687f   // 1/sqrt(32)
#define EPS      1e-9f

typedef __attribute__((ext_vector_type(4))) float f32x4;
typedef __attribute__((ext_vector_type(8))) short short8;

__device__ inline ushort f2bf(float f) {
    uint u = __float_as_uint(f);
    uint r = (u + 0x7FFF + ((u >> 16) & 1)) >> 16;   // round-to-nearest-even
    return (ushort)r;
}
__device__ inline float bf2f(ushort u) {
    return __uint_as_float(((uint)u) << 16);
}

// ---------------------------------------------------------------------------
// One-shot W conversion: fp32 W [K][N] -> bf16 W^T [N][K] for q,k,v
// ---------------------------------------------------------------------------
__global__ void conv_w_kernel(const float* __restrict__ Wq, const float* __restrict__ Wk,
                              const float* __restrict__ Wv,
                              ushort* __restrict__ WqT, ushort* __restrict__ WkT,
                              ushort* __restrict__ WvT)
{
    int i = blockIdx.x * blockDim.x + threadIdx.x;   // 0 .. 3*65536-1
    if (i >= 3 * IN_DIM * D_TOT) return;
    int w   = i >> 16;
    int rem = i & 65535;
    int k = rem >> 8, n = rem & 255;
    const float* W  = (w == 0) ? Wq  : (w == 1) ? Wk  : Wv;
    ushort*      WT = (w == 0) ? WqT : (w == 1) ? WkT : WvT;
    WT[n * IN_DIM + k] = f2bf(W[rem]);
}

// ---------------------------------------------------------------------------
// QKV GEMM, bf16 MFMA 16x16x32. Tile BM=128, BN=256 (full width), BK=32.
// 512 threads = 8 waves (2 row x 4 col). A staged from fp32 h with inline
// bf16 conversion. blockIdx.z selects q/k/v; k,v write into interleaved kvb.
// ---------------------------------------------------------------------------
__global__ __launch_bounds__(512) void qkv_gemm_mfma(
    const float* __restrict__ h,
    const ushort* __restrict__ WqT, const float* __restrict__ bq,
    const ushort* __restrict__ WkT, const float* __restrict__ bk,
    const ushort* __restrict__ WvT, const float* __restrict__ bv,
    ushort* __restrict__ qb, ushort* __restrict__ kvb,
    int M)
{
    const ushort* WT; const float* bias; ushort* outp; int ostride, coff;
    if (blockIdx.z == 0)      { WT = WqT; bias = bq; outp = qb;  ostride = 256; coff = 0;   }
    else if (blockIdx.z == 1) { WT = WkT; bias = bk; outp = kvb; ostride = 512; coff = 0;   }
    else                      { WT = WvT; bias = bv; outp = kvb; ostride = 512; coff = 256; }

    __shared__ ushort A_lds[128][40];   // pad 32->40 (80B stride)
    __shared__ ushort B_lds[256][40];

    const int tid  = threadIdx.x;
    const int m0   = blockIdx.x * 128;
    const int lane = tid & 63;
    const int wid  = tid >> 6;
    const int wr   = wid >> 2;        // 0..1 -> 64 rows
    const int wc   = wid & 3;         // 0..3 -> 64 cols
    const int l15  = lane & 15;
    const int l4   = lane >> 4;

    f32x4 acc[4][4] = {};

    #pragma unroll
    for (int k0 = 0; k0 < IN_DIM; k0 += 32) {
        // Stage A: 128 rows x 32 k, fp32 -> bf16 (8 fp32 per thread)
        {
            int r   = tid >> 2;       // 0..127
            int seg = tid & 3;        // 0..3
            int row = m0 + r;
            float4 f0 = make_float4(0.f, 0.f, 0.f, 0.f), f1 = f0;
            if (row < M) {
                const float* src = &h[(size_t)row * IN_DIM + k0 + seg * 8];
                f0 = *(const float4*)src;
                f1 = *(const float4*)(src + 4);
            }
            uint4 val;
            val.x = (uint)f2bf(f0.x) | ((uint)f2bf(f0.y) << 16);
            val.y = (uint)f2bf(f0.z) | ((uint)f2bf(f0.w) << 16);
            val.z = (uint)f2bf(f1.x) | ((uint)f2bf(f1.y) << 16);
            val.w = (uint)f2bf(f1.z) | ((uint)f2bf(f1.w) << 16);
            *(uint4*)&A_lds[r][seg * 8] = val;
        }
        // Stage B^T: 256 cols x 32 k (bf16, 16 per thread)
        #pragma unroll
        for (int it = 0; it < 2; ++it) {
            int v   = tid + it * 512;     // 0..1023
            int col = v >> 2, seg = v & 3;
            *(uint4*)&B_lds[col][seg * 8] =
                *(const uint4*)&WT[(size_t)col * IN_DIM + k0 + seg * 8];
        }
        __syncthreads();

        short8 afr[4], bfr[4];
        #pragma unroll
        for (int mi = 0; mi < 4; ++mi)
            afr[mi] = *(const short8*)&A_lds[wr * 64 + mi * 16 + l15][l4 * 8];
        #pragma unroll
        for (int ni = 0; ni < 4; ++ni)
            bfr[ni] = *(const short8*)&B_lds[wc * 64 + ni * 16 + l15][l4 * 8];
        #pragma unroll
        for (int mi = 0; mi < 4; ++mi)
            #pragma unroll
            for (int ni = 0; ni < 4; ++ni)
                acc[mi][ni] = __builtin_amdgcn_mfma_f32_16x16x32_bf16(
                    afr[mi], bfr[ni], acc[mi][ni], 0, 0, 0);
        __syncthreads();
    }

    float bias_c[4];
    #pragma unroll
    for (int ni = 0; ni < 4; ++ni)
        bias_c[ni] = bias[wc * 64 + ni * 16 + l15];

    #pragma unroll
    for (int mi = 0; mi < 4; ++mi) {
        #pragma unroll
        for (int r = 0; r < 4; ++r) {
            int row_g = m0 + wr * 64 + mi * 16 + l4 * 4 + r;
            if (row_g < M) {
                #pragma unroll
                for (int ni = 0; ni < 4; ++ni) {
                    int col_g = wc * 64 + ni * 16 + l15;
                    outp[(size_t)row_g * ostride + coff + col_g] =
                        f2bf(acc[mi][ni][r] + bias_c[ni]);
                }
            }
        }
    }
}

// ---------------------------------------------------------------------------
// CSR build: histogram, scan (8 elems/thread), scatter
// ---------------------------------------------------------------------------
__global__ void hist_kernel(const int* __restrict__ dst, int* __restrict__ counts, int E)
{
    int i = blockIdx.x * blockDim.x + threadIdx.x;
    if (i < E) atomicAdd(&counts[dst[i]], 1);
}

__global__ __launch_bounds__(1024) void scan_kernel(
    const int* __restrict__ counts, int* __restrict__ offs,
    int* __restrict__ cursor, int n)
{
    __shared__ int wsum[16];
    __shared__ int carry_s;
    const int tid  = threadIdx.x;
    const int lane = tid & 63;
    const int wid  = tid >> 6;
    if (tid == 0) carry_s = 0;
    __syncthreads();

    const int PER_ITER = 1024 * 8;
    for (int base = 0; base < n; base += PER_ITER) {
        int i0 = base + tid * 8;
        int x[8];
        if (i0 + 7 < n) {
            int4 a = *(const int4*)&counts[i0];
            int4 b = *(const int4*)&counts[i0 + 4];
            x[0]=a.x; x[1]=a.y; x[2]=a.z; x[3]=a.w;
            x[4]=b.x; x[5]=b.y; x[6]=b.z; x[7]=b.w;
        } else {
            #pragma unroll
            for (int j = 0; j < 8; ++j) { int i = i0 + j; x[j] = (i < n) ? counts[i] : 0; }
        }
        int tot = 0;
        #pragma unroll
        for (int j = 0; j < 8; ++j) { int t = x[j]; x[j] = tot; tot += t; }
        int v = tot;
        #pragma unroll
        for (int off = 1; off < 64; off <<= 1) { int t = __shfl_up(v, off); if (lane >= off) v += t; }
        if (lane == 63) wsum[wid] = v;
        __syncthreads();
        if (wid == 0) {
            int wv = (lane < 16) ? wsum[lane] : 0;
            #pragma unroll
            for (int off = 1; off < 16; off <<= 1) { int t = __shfl_up(wv, off); if (lane >= off) wv += t; }
            if (lane < 16) wsum[lane] = wv;
        }
        __syncthreads();
        int wbase    = (wid > 0) ? wsum[wid - 1] : 0;
        int thr_excl = wbase + v - tot;
        int carry    = carry_s;
        #pragma unroll
        for (int j = 0; j < 8; ++j) {
            int i = i0 + j;
            if (i < n) { int o = carry + thr_excl + x[j]; offs[i] = o; cursor[i] = o; }
        }
        __syncthreads();
        if (tid == 1023) carry_s = carry + wbase + v;
        __syncthreads();
    }
    if (tid == 0) offs[n] = carry_s;
}

__global__ void scatter_kernel(const int* __restrict__ src, const int* __restrict__ dst,
                               int* __restrict__ cursor, int* __restrict__ csr, int E)
{
    int i = blockIdx.x * blockDim.x + threadIdx.x;
    if (i < E) {
        int p = atomicAdd(&cursor[dst[i]], 1);
        csr[p] = src[i];
    }
}

// ---------------------------------------------------------------------------
// Attention aggregation: one wave per destination node.
// kvb interleaved: node's k at [node*512 .. +255], v at [+256 .. +511].
// 2-edge unroll for MLP; nontemporal output store (don't evict kv).
// ---------------------------------------------------------------------------
__global__ __launch_bounds__(256) void attn_kernel(
    const ushort* __restrict__ qb, const ushort* __restrict__ kvb,
    const int* __restrict__ offs, const int* __restrict__ csr,
    float* __restrict__ out, int n)
{
    int wave = (int)((blockIdx.x * (size_t)blockDim.x + threadIdx.x) >> 6);
    if (wave >= n) return;
    const int lane = threadIdx.x & 63;
    const int j0   = lane * 4;

    ushort4 qu = *(const ushort4*)&qb[(size_t)wave * D_TOT + j0];
    float q0 = bf2f(qu.x), q1 = bf2f(qu.y), q2 = bf2f(qu.z), q3 = bf2f(qu.w);

    float acc0 = 0.f, acc1 = 0.f, acc2 = 0.f, acc3 = 0.f, z = 0.f;

    int p = offs[wave];
    const int pend = offs[wave + 1];

    for (; p + 2 <= pend; p += 2) {
        int s0 = csr[p], s1 = csr[p + 1];
        const ushort* b0 = &kvb[(size_t)s0 * 512 + j0];
        const ushort* b1 = &kvb[(size_t)s1 * 512 + j0];
        ushort4 k0u = *(const ushort4*)b0;
        ushort4 v0u = *(const ushort4*)(b0 + 256);
        ushort4 k1u = *(const ushort4*)b1;
        ushort4 v1u = *(const ushort4*)(b1 + 256);

        float d0 = bf2f(k0u.x) * q0 + bf2f(k0u.y) * q1 + bf2f(k0u.z) * q2 + bf2f(k0u.w) * q3;
        float d1 = bf2f(k1u.x) * q0 + bf2f(k1u.y) * q1 + bf2f(k1u.z) * q2 + bf2f(k1u.w) * q3;
        d0 += __shfl_xor(d0, 1);  d1 += __shfl_xor(d1, 1);
        d0 += __shfl_xor(d0, 2);  d1 += __shfl_xor(d1, 2);
        d0 += __shfl_xor(d0, 4);  d1 += __shfl_xor(d1, 4);
        float sc0 = __expf(d0 * SCALE);
        float sc1 = __expf(d1 * SCALE);
        acc0 += sc0 * bf2f(v0u.x) + sc1 * bf2f(v1u.x);
        acc1 += sc0 * bf2f(v0u.y) + sc1 * bf2f(v1u.y);
        acc2 += sc0 * bf2f(v0u.z) + sc1 * bf2f(v1u.z);
        acc3 += sc0 * bf2f(v0u.w) + sc1 * bf2f(v1u.w);
        z += sc0 + sc1;
    }
    if (p < pend) {
        int s = csr[p];
        const ushort* b = &kvb[(size_t)s * 512 + j0];
        ushort4 ku = *(const ushort4*)b;
        ushort4 vu = *(const ushort4*)(b + 256);
        float d = bf2f(ku.x) * q0 + bf2f(ku.y) * q1 + bf2f(ku.z) * q2 + bf2f(ku.w) * q3;
        d += __shfl_xor(d, 1);
        d += __shfl_xor(d, 2);
        d += __shfl_xor(d, 4);
        float sc = __expf(d * SCALE);
        acc0 += sc * bf2f(vu.x);
        acc1 += sc * bf2f(vu.y);
        acc2 += sc * bf2f(vu.z);
        acc3 += sc * bf2f(vu.w);
        z += sc;
    }

    float inv = 1.0f / (z + EPS);
    f32x4 o;
    o[0] = acc0 * inv; o[1] = acc1 * inv; o[2] = acc2 * inv; o[3] = acc3 * inv;
    __builtin_nontemporal_store(o, (f32x4*)&out[(size_t)wave * D_TOT + j0]);
}

// ---------------------------------------------------------------------------
extern "C" void kernel_launch(void* const* d_in, const int* in_sizes, int n_in,
                              void* d_out, int out_size, void* d_ws, size_t ws_size,
                              hipStream_t stream)
{
    const float* h   = (const float*)d_in[0];
    const int*   src = (const int*)  d_in[1];
    const int*   dst = (const int*)  d_in[2];
    const float* Wq  = (const float*)d_in[3];
    const float* bq  = (const float*)d_in[4];
    const float* Wk  = (const float*)d_in[5];
    const float* bk  = (const float*)d_in[6];
    const float* Wv  = (const float*)d_in[7];
    const float* bv  = (const float*)d_in[8];
    float* out = (float*)d_out;

    const int N = in_sizes[0] / IN_DIM;
    const int E = in_sizes[1];

    // Workspace layout: qb (bf16 [N][256]) | kvb (bf16 [N][512] interleaved)
    //                   | WT x3 | offs | cursor | counts | csr   (~84 MB)
    ushort* qb  = (ushort*)d_ws;
    ushort* kvb = qb + (size_t)N * D_TOT;
    ushort* WqT = kvb + (size_t)N * 512;
    ushort* WkT = WqT + D_TOT * IN_DIM;
    ushort* WvT = WkT + D_TOT * IN_DIM;
    int* offs   = (int*)(WvT + D_TOT * IN_DIM);
    int* cursor = offs + (N + 8);
    int* counts = cursor + (N + 8);
    int* csr    = counts + N;

    // 1) W -> bf16 transposed (single small launch)
    conv_w_kernel<<<(3 * IN_DIM * D_TOT + 255) / 256, 256, 0, stream>>>(
        Wq, Wk, Wv, WqT, WkT, WvT);

    // 2) QKV projection (bf16 MFMA, fused h conversion, full-width tile)
    {
        dim3 grid((N + 127) / 128, 1, 3);
        qkv_gemm_mfma<<<grid, 512, 0, stream>>>(h, WqT, bq, WkT, bk, WvT, bv,
                                                qb, kvb, N);
    }
    // 3) CSR by destination
    (void)hipMemsetAsync(counts, 0, (size_t)N * sizeof(int), stream);
    {
        int blocks = (E + 255) / 256;
        hist_kernel<<<blocks, 256, 0, stream>>>(dst, counts, E);
        scan_kernel<<<1, 1024, 0, stream>>>(counts, offs, cursor, N);
        scatter_kernel<<<blocks, 256, 0, stream>>>(src, dst, cursor, csr, E);
    }
    // 4) Per-node attention aggregation (1 wave per node)
    {
        int blocks = (N + 3) / 4;
        attn_kernel<<<blocks, 256, 0, stream>>>(qb, kvb, offs, csr, out, N);
    }
}

// Round 5
// 493.056 us; speedup vs baseline: 1.9123x; 1.1053x over previous
//
#include <hip/hip_runtime.h>
#include <hip/hip_bf16.h>

#define IN_DIM   256
#define NUM_HEAD 8
#define OUT_DIM  32
#define D_TOT    256
#define SCALE    0.17677669529663687f   // 1/sqrt(32)
#define EPS      1e-9f

typedef __attribute__((ext_vector_type(4))) float f32x4;
typedef __attribute__((ext_vector_type(8))) short short8;

__device__ inline ushort f2bf(float f) {
    uint u = __float_as_uint(f);
    uint r = (u + 0x7FFF + ((u >> 16) & 1)) >> 16;   // round-to-nearest-even
    return (ushort)r;
}
__device__ inline float bf2f(ushort u) {
    return __uint_as_float(((uint)u) << 16);
}

// ---------------------------------------------------------------------------
// One-shot W conversion: fp32 W [K][N] -> bf16 W^T [N][K] for q,k,v
// ---------------------------------------------------------------------------
__global__ void conv_w_kernel(const float* __restrict__ Wq, const float* __restrict__ Wk,
                              const float* __restrict__ Wv,
                              ushort* __restrict__ WqT, ushort* __restrict__ WkT,
                              ushort* __restrict__ WvT)
{
    int i = blockIdx.x * blockDim.x + threadIdx.x;   // 0 .. 3*65536-1
    if (i >= 3 * IN_DIM * D_TOT) return;
    int w   = i >> 16;
    int rem = i & 65535;
    int k = rem >> 8, n = rem & 255;
    const float* W  = (w == 0) ? Wq  : (w == 1) ? Wk  : Wv;
    ushort*      WT = (w == 0) ? WqT : (w == 1) ? WkT : WvT;
    WT[n * IN_DIM + k] = f2bf(W[rem]);
}

// ---------------------------------------------------------------------------
// QKV GEMM, bf16 MFMA 16x16x32. BM=64 rows/block, 256 thr = 4 waves.
// A (bf16, full K=256) staged in LDS ONCE from fp32 h; then z-loop over
// q/k/v re-staging only B^T (L2-resident weights). Wave w owns cols
// [w*64, w*64+64); all waves cover all 64 rows.
// ---------------------------------------------------------------------------
__global__ __launch_bounds__(256) void qkv_gemm_mfma(
    const float* __restrict__ h,
    const ushort* __restrict__ WqT, const float* __restrict__ bq,
    const ushort* __restrict__ WkT, const float* __restrict__ bk,
    const ushort* __restrict__ WvT, const float* __restrict__ bv,
    ushort* __restrict__ qb, ushort* __restrict__ kvb,
    int M)
{
    __shared__ ushort A_lds[64][264];   // full-K rows, pad 256->264 (16B-aligned)
    __shared__ ushort B_lds[256][40];   // per-kstep, pad 32->40

    const int tid  = threadIdx.x;
    const int m0   = blockIdx.x * 64;
    const int lane = tid & 63;
    const int wid  = tid >> 6;        // 0..3 -> col panel of 64
    const int l15  = lane & 15;
    const int l4   = lane >> 4;

    // Stage A once: thread t covers row r=t>>2, k-quarter qd=t&3 (64 k elems)
    {
        int r   = tid >> 2;
        int qd  = tid & 3;
        int row = m0 + r;
        #pragma unroll
        for (int i = 0; i < 8; ++i) {
            int k = qd * 64 + i * 8;
            float4 f0 = make_float4(0.f, 0.f, 0.f, 0.f), f1 = f0;
            if (row < M) {
                const float* src = &h[(size_t)row * IN_DIM + k];
                f0 = *(const float4*)src;
                f1 = *(const float4*)(src + 4);
            }
            uint4 val;
            val.x = (uint)f2bf(f0.x) | ((uint)f2bf(f0.y) << 16);
            val.y = (uint)f2bf(f0.z) | ((uint)f2bf(f0.w) << 16);
            val.z = (uint)f2bf(f1.x) | ((uint)f2bf(f1.y) << 16);
            val.w = (uint)f2bf(f1.z) | ((uint)f2bf(f1.w) << 16);
            *(uint4*)&A_lds[r][k] = val;
        }
    }
    __syncthreads();

    #pragma unroll
    for (int z = 0; z < 3; ++z) {
        const ushort* WT   = (z == 0) ? WqT : (z == 1) ? WkT : WvT;
        const float*  bias = (z == 0) ? bq  : (z == 1) ? bk  : bv;
        ushort* outp  = (z == 0) ? qb : kvb;
        const int ostride = (z == 0) ? 256 : 512;
        const int coff    = (z == 2) ? 256 : 0;

        f32x4 acc[4][4] = {};   // [mi rows][ni cols]

        for (int k0 = 0; k0 < IN_DIM; k0 += 32) {
            // Stage B^T: 256 cols x 32 k = 1024 x 8-elem chunks, 4 per thread
            #pragma unroll
            for (int it = 0; it < 4; ++it) {
                int v   = tid + it * 256;
                int col = v >> 2, seg = v & 3;
                *(uint4*)&B_lds[col][seg * 8] =
                    *(const uint4*)&WT[(size_t)col * IN_DIM + k0 + seg * 8];
            }
            __syncthreads();

            short8 afr[4], bfr[4];
            #pragma unroll
            for (int mi = 0; mi < 4; ++mi)
                afr[mi] = *(const short8*)&A_lds[mi * 16 + l15][k0 + l4 * 8];
            #pragma unroll
            for (int ni = 0; ni < 4; ++ni)
                bfr[ni] = *(const short8*)&B_lds[wid * 64 + ni * 16 + l15][l4 * 8];
            #pragma unroll
            for (int mi = 0; mi < 4; ++mi)
                #pragma unroll
                for (int ni = 0; ni < 4; ++ni)
                    acc[mi][ni] = __builtin_amdgcn_mfma_f32_16x16x32_bf16(
                        afr[mi], bfr[ni], acc[mi][ni], 0, 0, 0);
            __syncthreads();
        }

        float bias_c[4];
        #pragma unroll
        for (int ni = 0; ni < 4; ++ni)
            bias_c[ni] = bias[wid * 64 + ni * 16 + l15];

        #pragma unroll
        for (int mi = 0; mi < 4; ++mi) {
            #pragma unroll
            for (int r = 0; r < 4; ++r) {
                int row_g = m0 + mi * 16 + l4 * 4 + r;
                if (row_g < M) {
                    #pragma unroll
                    for (int ni = 0; ni < 4; ++ni) {
                        int col_g = wid * 64 + ni * 16 + l15;
                        outp[(size_t)row_g * ostride + coff + col_g] =
                            f2bf(acc[mi][ni][r] + bias_c[ni]);
                    }
                }
            }
        }
        // acc re-zeroed at top of next z; B_lds re-staged after epilogue is
        // safe: next z's first stage has a __syncthreads before frag reads,
        // and epilogue reads only registers.
    }
}

// ---------------------------------------------------------------------------
// CSR build: histogram (4 edges/thread), hierarchical scan, scatter
// ---------------------------------------------------------------------------
__global__ void hist_kernel(const int* __restrict__ dst, int* __restrict__ counts, int E)
{
    int i0 = (blockIdx.x * blockDim.x + threadIdx.x) * 4;
    if (i0 + 3 < E) {
        int4 d = *(const int4*)&dst[i0];
        atomicAdd(&counts[d.x], 1);
        atomicAdd(&counts[d.y], 1);
        atomicAdd(&counts[d.z], 1);
        atomicAdd(&counts[d.w], 1);
    } else {
        for (int j = 0; j < 4; ++j) {
            int i = i0 + j;
            if (i < E) atomicAdd(&counts[dst[i]], 1);
        }
    }
}

// scan1: each 256-thr block scans 1024 counts (padded region is zeroed),
// writes block-local exclusive prefix into offs, block total into bsums.
__global__ __launch_bounds__(256) void scan1_kernel(
    const int* __restrict__ counts, int* __restrict__ offs, int* __restrict__ bsums)
{
    __shared__ int wsum[4];
    const int tid  = threadIdx.x;
    const int lane = tid & 63;
    const int wid  = tid >> 6;
    const int i0   = blockIdx.x * 1024 + tid * 4;

    int4 c = *(const int4*)&counts[i0];
    int t0 = c.x, t1 = t0 + c.y, t2 = t1 + c.z, t3 = t2 + c.w;  // inclusive in-thread
    int v = t3;
    #pragma unroll
    for (int off = 1; off < 64; off <<= 1) {
        int t = __shfl_up(v, off);
        if (lane >= off) v += t;
    }
    int excl = v - t3;                 // wave-exclusive for this thread
    if (lane == 63) wsum[wid] = v;     // wave total
    __syncthreads();
    if (tid == 0) {
        int s0 = wsum[0], s1 = wsum[1], s2 = wsum[2], s3 = wsum[3];
        wsum[0] = 0; wsum[1] = s0; wsum[2] = s0 + s1; wsum[3] = s0 + s1 + s2;
        bsums[blockIdx.x] = s0 + s1 + s2 + s3;
    }
    __syncthreads();
    int base = wsum[wid] + excl;
    offs[i0 + 0] = base;
    offs[i0 + 1] = base + t0;
    offs[i0 + 2] = base + t1;
    offs[i0 + 3] = base + t2;
}

// scan2: single wave scans block sums (nb <= 64) in place -> exclusive;
// writes grand total to offs[N].
__global__ void scan2_kernel(int* __restrict__ bsums, int* __restrict__ offs_N, int nb)
{
    int lane = threadIdx.x;
    int x = (lane < nb) ? bsums[lane] : 0;
    int v = x;
    #pragma unroll
    for (int off = 1; off < 64; off <<= 1) {
        int t = __shfl_up(v, off);
        if (lane >= off) v += t;
    }
    if (lane < nb) bsums[lane] = v - x;
    if (lane == 63) *offs_N = v;
}

// scan3: add block base; materialize cursor. Never touches offs[N].
__global__ __launch_bounds__(256) void scan3_kernel(
    int* __restrict__ offs, int* __restrict__ cursor,
    const int* __restrict__ bsums, int n)
{
    int base = bsums[blockIdx.x];
    int i0 = blockIdx.x * 1024 + threadIdx.x * 4;
    if (i0 + 3 < n) {
        int4 o = *(const int4*)&offs[i0];
        o.x += base; o.y += base; o.z += base; o.w += base;
        *(int4*)&offs[i0]   = o;
        *(int4*)&cursor[i0] = o;
    } else {
        for (int j = 0; j < 4; ++j) {
            int i = i0 + j;
            if (i < n) { int o = offs[i] + base; offs[i] = o; cursor[i] = o; }
        }
    }
}

__global__ void scatter_kernel(const int* __restrict__ src, const int* __restrict__ dst,
                               int* __restrict__ cursor, int* __restrict__ csr, int E)
{
    int i0 = (blockIdx.x * blockDim.x + threadIdx.x) * 4;
    if (i0 + 3 < E) {
        int4 s = *(const int4*)&src[i0];
        int4 d = *(const int4*)&dst[i0];
        int p0 = atomicAdd(&cursor[d.x], 1); csr[p0] = s.x;
        int p1 = atomicAdd(&cursor[d.y], 1); csr[p1] = s.y;
        int p2 = atomicAdd(&cursor[d.z], 1); csr[p2] = s.z;
        int p3 = atomicAdd(&cursor[d.w], 1); csr[p3] = s.w;
    } else {
        for (int j = 0; j < 4; ++j) {
            int i = i0 + j;
            if (i < E) {
                int p = atomicAdd(&cursor[dst[i]], 1);
                csr[p] = src[i];
            }
        }
    }
}

// ---------------------------------------------------------------------------
// Attention aggregation: one wave per destination node, 4-edge unroll.
// kvb interleaved: node's k at [node*512 .. +255], v at [+256 .. +511].
// ---------------------------------------------------------------------------
__global__ __launch_bounds__(256) void attn_kernel(
    const ushort* __restrict__ qb, const ushort* __restrict__ kvb,
    const int* __restrict__ offs, const int* __restrict__ csr,
    float* __restrict__ out, int n)
{
    int wave = (int)((blockIdx.x * (size_t)blockDim.x + threadIdx.x) >> 6);
    if (wave >= n) return;
    const int lane = threadIdx.x & 63;
    const int j0   = lane * 4;

    ushort4 qu = *(const ushort4*)&qb[(size_t)wave * D_TOT + j0];
    float q0 = bf2f(qu.x), q1 = bf2f(qu.y), q2 = bf2f(qu.z), q3 = bf2f(qu.w);

    float acc0 = 0.f, acc1 = 0.f, acc2 = 0.f, acc3 = 0.f, z = 0.f;

    int p = offs[wave];
    const int pend = offs[wave + 1];

    for (; p + 4 <= pend; p += 4) {
        int s0 = csr[p], s1 = csr[p + 1], s2 = csr[p + 2], s3 = csr[p + 3];
        const ushort* b0 = &kvb[(size_t)s0 * 512 + j0];
        const ushort* b1 = &kvb[(size_t)s1 * 512 + j0];
        const ushort* b2 = &kvb[(size_t)s2 * 512 + j0];
        const ushort* b3 = &kvb[(size_t)s3 * 512 + j0];
        ushort4 k0u = *(const ushort4*)b0;  ushort4 v0u = *(const ushort4*)(b0 + 256);
        ushort4 k1u = *(const ushort4*)b1;  ushort4 v1u = *(const ushort4*)(b1 + 256);
        ushort4 k2u = *(const ushort4*)b2;  ushort4 v2u = *(const ushort4*)(b2 + 256);
        ushort4 k3u = *(const ushort4*)b3;  ushort4 v3u = *(const ushort4*)(b3 + 256);

        float d0 = bf2f(k0u.x) * q0 + bf2f(k0u.y) * q1 + bf2f(k0u.z) * q2 + bf2f(k0u.w) * q3;
        float d1 = bf2f(k1u.x) * q0 + bf2f(k1u.y) * q1 + bf2f(k1u.z) * q2 + bf2f(k1u.w) * q3;
        float d2 = bf2f(k2u.x) * q0 + bf2f(k2u.y) * q1 + bf2f(k2u.z) * q2 + bf2f(k2u.w) * q3;
        float d3 = bf2f(k3u.x) * q0 + bf2f(k3u.y) * q1 + bf2f(k3u.z) * q2 + bf2f(k3u.w) * q3;
        d0 += __shfl_xor(d0, 1); d1 += __shfl_xor(d1, 1); d2 += __shfl_xor(d2, 1); d3 += __shfl_xor(d3, 1);
        d0 += __shfl_xor(d0, 2); d1 += __shfl_xor(d1, 2); d2 += __shfl_xor(d2, 2); d3 += __shfl_xor(d3, 2);
        d0 += __shfl_xor(d0, 4); d1 += __shfl_xor(d1, 4); d2 += __shfl_xor(d2, 4); d3 += __shfl_xor(d3, 4);
        float sc0 = __expf(d0 * SCALE);
        float sc1 = __expf(d1 * SCALE);
        float sc2 = __expf(d2 * SCALE);
        float sc3 = __expf(d3 * SCALE);
        acc0 += sc0 * bf2f(v0u.x) + sc1 * bf2f(v1u.x) + sc2 * bf2f(v2u.x) + sc3 * bf2f(v3u.x);
        acc1 += sc0 * bf2f(v0u.y) + sc1 * bf2f(v1u.y) + sc2 * bf2f(v2u.y) + sc3 * bf2f(v3u.y);
        acc2 += sc0 * bf2f(v0u.z) + sc1 * bf2f(v1u.z) + sc2 * bf2f(v2u.z) + sc3 * bf2f(v3u.z);
        acc3 += sc0 * bf2f(v0u.w) + sc1 * bf2f(v1u.w) + sc2 * bf2f(v2u.w) + sc3 * bf2f(v3u.w);
        z += sc0 + sc1 + sc2 + sc3;
    }
    for (; p < pend; ++p) {
        int s = csr[p];
        const ushort* b = &kvb[(size_t)s * 512 + j0];
        ushort4 ku = *(const ushort4*)b;
        ushort4 vu = *(const ushort4*)(b + 256);
        float d = bf2f(ku.x) * q0 + bf2f(ku.y) * q1 + bf2f(ku.z) * q2 + bf2f(ku.w) * q3;
        d += __shfl_xor(d, 1);
        d += __shfl_xor(d, 2);
        d += __shfl_xor(d, 4);
        float sc = __expf(d * SCALE);
        acc0 += sc * bf2f(vu.x);
        acc1 += sc * bf2f(vu.y);
        acc2 += sc * bf2f(vu.z);
        acc3 += sc * bf2f(vu.w);
        z += sc;
    }

    float inv = 1.0f / (z + EPS);
    f32x4 o;
    o[0] = acc0 * inv; o[1] = acc1 * inv; o[2] = acc2 * inv; o[3] = acc3 * inv;
    __builtin_nontemporal_store(o, (f32x4*)&out[(size_t)wave * D_TOT + j0]);
}

// ---------------------------------------------------------------------------
extern "C" void kernel_launch(void* const* d_in, const int* in_sizes, int n_in,
                              void* d_out, int out_size, void* d_ws, size_t ws_size,
                              hipStream_t stream)
{
    const float* h   = (const float*)d_in[0];
    const int*   src = (const int*)  d_in[1];
    const int*   dst = (const int*)  d_in[2];
    const float* Wq  = (const float*)d_in[3];
    const float* bq  = (const float*)d_in[4];
    const float* Wk  = (const float*)d_in[5];
    const float* bk  = (const float*)d_in[6];
    const float* Wv  = (const float*)d_in[7];
    const float* bv  = (const float*)d_in[8];
    float* out = (float*)d_out;

    const int N = in_sizes[0] / IN_DIM;
    const int E = in_sizes[1];
    const int nb   = (N + 1023) / 1024;   // scan blocks
    const int npad = nb * 1024;           // padded counts length

    // Workspace: qb bf16[N][256] | kvb bf16[N][512] | WT x3 | offs[N+8] |
    //            cursor[N+8] | counts[npad] | bsums[64] | csr[E]
    ushort* qb  = (ushort*)d_ws;
    ushort* kvb = qb + (size_t)N * D_TOT;
    ushort* WqT = kvb + (size_t)N * 512;
    ushort* WkT = WqT + D_TOT * IN_DIM;
    ushort* WvT = WkT + D_TOT * IN_DIM;
    int* offs   = (int*)(WvT + D_TOT * IN_DIM);
    int* cursor = offs + (N + 8);
    int* counts = cursor + (N + 8);
    int* bsums  = counts + npad;
    int* csr    = bsums + 64;

    // 1) W -> bf16 transposed
    conv_w_kernel<<<(3 * IN_DIM * D_TOT + 255) / 256, 256, 0, stream>>>(
        Wq, Wk, Wv, WqT, WkT, WvT);

    // 2) QKV projection: single pass over h, z-loop inside block
    qkv_gemm_mfma<<<(N + 63) / 64, 256, 0, stream>>>(
        h, WqT, bq, WkT, bk, WvT, bv, qb, kvb, N);

    // 3) CSR by destination
    (void)hipMemsetAsync(counts, 0, (size_t)npad * sizeof(int), stream);
    {
        int eblocks = (E / 4 + 255) / 256;
        hist_kernel<<<eblocks, 256, 0, stream>>>(dst, counts, E);
        scan1_kernel<<<nb, 256, 0, stream>>>(counts, offs, bsums);
        scan2_kernel<<<1, 64, 0, stream>>>(bsums, offs + N, nb);
        scan3_kernel<<<nb, 256, 0, stream>>>(offs, cursor, bsums, N);
        scatter_kernel<<<eblocks, 256, 0, stream>>>(src, dst, cursor, csr, E);
    }
    // 4) Per-node attention aggregation (1 wave per node)
    attn_kernel<<<(N + 3) / 4, 256, 0, stream>>>(qb, kvb, offs, csr, out, N);
}

// Round 6
// 346.926 us; speedup vs baseline: 2.7178x; 1.4212x over previous
//
#include <hip/hip_runtime.h>
#include <hip/hip_bf16.h>

#define IN_DIM   256
#define NUM_HEAD 8
#define OUT_DIM  32
#define D_TOT    256
#define SCALE    0.17677669529663687f   // 1/sqrt(32)
#define EPS      1e-9f
#define CAP      128                    // bucket capacity per node (17 sigma)

typedef __attribute__((ext_vector_type(4))) float f32x4;
typedef __attribute__((ext_vector_type(2))) float f32x2;
typedef __attribute__((ext_vector_type(8))) short short8;

__device__ inline ushort f2bf(float f) {
    uint u = __float_as_uint(f);
    uint r = (u + 0x7FFF + ((u >> 16) & 1)) >> 16;   // round-to-nearest-even
    return (ushort)r;
}
__device__ inline float bf2f(ushort u) {
    return __uint_as_float(((uint)u) << 16);
}
__device__ inline uchar f2fp8(float f) {
    int p = __builtin_amdgcn_cvt_pk_fp8_f32(f, f, 0, false);
    return (uchar)(p & 0xff);
}

// ---------------------------------------------------------------------------
// One-shot W conversion: fp32 W [K][N] -> bf16 W^T [N][K] for q,k,v
// ---------------------------------------------------------------------------
__global__ void conv_w_kernel(const float* __restrict__ Wq, const float* __restrict__ Wk,
                              const float* __restrict__ Wv,
                              ushort* __restrict__ WqT, ushort* __restrict__ WkT,
                              ushort* __restrict__ WvT)
{
    int i = blockIdx.x * blockDim.x + threadIdx.x;   // 0 .. 3*65536-1
    if (i >= 3 * IN_DIM * D_TOT) return;
    int w   = i >> 16;
    int rem = i & 65535;
    int k = rem >> 8, n = rem & 255;
    const float* W  = (w == 0) ? Wq  : (w == 1) ? Wk  : Wv;
    ushort*      WT = (w == 0) ? WqT : (w == 1) ? WkT : WvT;
    WT[n * IN_DIM + k] = f2bf(W[rem]);
}

// ---------------------------------------------------------------------------
// QKV GEMM, bf16 MFMA 16x16x32. BM=64 rows/block, 256 thr = 4 waves.
// A (bf16, full K=256) staged in LDS ONCE from fp32 h; z-loop over q/k/v
// re-staging only B^T (L2-resident weights). Wave w owns cols [w*64,+64).
// Epilogue: q -> bf16 qb[N][256]; k -> fp8 blob[row][0..255];
//           v -> bf16 blob[row][256..767].
// ---------------------------------------------------------------------------
__global__ __launch_bounds__(256) void qkv_gemm_mfma(
    const float* __restrict__ h,
    const ushort* __restrict__ WqT, const float* __restrict__ bq,
    const ushort* __restrict__ WkT, const float* __restrict__ bk,
    const ushort* __restrict__ WvT, const float* __restrict__ bv,
    ushort* __restrict__ qb, uchar* __restrict__ blob,
    int M)
{
    __shared__ ushort A_lds[64][264];   // full-K rows, pad 256->264
    __shared__ ushort B_lds[256][40];   // per-kstep, pad 32->40

    const int tid  = threadIdx.x;
    const int m0   = blockIdx.x * 64;
    const int lane = tid & 63;
    const int wid  = tid >> 6;        // 0..3 -> col panel of 64
    const int l15  = lane & 15;
    const int l4   = lane >> 4;

    // Stage A once: thread t covers row r=t>>2, k-quarter qd=t&3 (64 k elems)
    {
        int r   = tid >> 2;
        int qd  = tid & 3;
        int row = m0 + r;
        #pragma unroll
        for (int i = 0; i < 8; ++i) {
            int k = qd * 64 + i * 8;
            float4 f0 = make_float4(0.f, 0.f, 0.f, 0.f), f1 = f0;
            if (row < M) {
                const float* src = &h[(size_t)row * IN_DIM + k];
                f0 = *(const float4*)src;
                f1 = *(const float4*)(src + 4);
            }
            uint4 val;
            val.x = (uint)f2bf(f0.x) | ((uint)f2bf(f0.y) << 16);
            val.y = (uint)f2bf(f0.z) | ((uint)f2bf(f0.w) << 16);
            val.z = (uint)f2bf(f1.x) | ((uint)f2bf(f1.y) << 16);
            val.w = (uint)f2bf(f1.z) | ((uint)f2bf(f1.w) << 16);
            *(uint4*)&A_lds[r][k] = val;
        }
    }
    __syncthreads();

    #pragma unroll
    for (int z = 0; z < 3; ++z) {
        const ushort* WT   = (z == 0) ? WqT : (z == 1) ? WkT : WvT;
        const float*  bias = (z == 0) ? bq  : (z == 1) ? bk  : bv;

        f32x4 acc[4][4] = {};   // [mi rows][ni cols]

        for (int k0 = 0; k0 < IN_DIM; k0 += 32) {
            #pragma unroll
            for (int it = 0; it < 4; ++it) {
                int v   = tid + it * 256;
                int col = v >> 2, seg = v & 3;
                *(uint4*)&B_lds[col][seg * 8] =
                    *(const uint4*)&WT[(size_t)col * IN_DIM + k0 + seg * 8];
            }
            __syncthreads();

            short8 afr[4], bfr[4];
            #pragma unroll
            for (int mi = 0; mi < 4; ++mi)
                afr[mi] = *(const short8*)&A_lds[mi * 16 + l15][k0 + l4 * 8];
            #pragma unroll
            for (int ni = 0; ni < 4; ++ni)
                bfr[ni] = *(const short8*)&B_lds[wid * 64 + ni * 16 + l15][l4 * 8];
            #pragma unroll
            for (int mi = 0; mi < 4; ++mi)
                #pragma unroll
                for (int ni = 0; ni < 4; ++ni)
                    acc[mi][ni] = __builtin_amdgcn_mfma_f32_16x16x32_bf16(
                        afr[mi], bfr[ni], acc[mi][ni], 0, 0, 0);
            __syncthreads();
        }

        float bias_c[4];
        #pragma unroll
        for (int ni = 0; ni < 4; ++ni)
            bias_c[ni] = bias[wid * 64 + ni * 16 + l15];

        #pragma unroll
        for (int mi = 0; mi < 4; ++mi) {
            #pragma unroll
            for (int r = 0; r < 4; ++r) {
                int row_g = m0 + mi * 16 + l4 * 4 + r;
                if (row_g < M) {
                    #pragma unroll
                    for (int ni = 0; ni < 4; ++ni) {
                        int   col_g = wid * 64 + ni * 16 + l15;
                        float val   = acc[mi][ni][r] + bias_c[ni];
                        if (z == 0) {
                            qb[(size_t)row_g * 256 + col_g] = f2bf(val);
                        } else if (z == 1) {
                            blob[(size_t)row_g * 768 + col_g] = f2fp8(val);
                        } else {
                            *(ushort*)(blob + (size_t)row_g * 768 + 256 + col_g * 2) = f2bf(val);
                        }
                    }
                }
            }
        }
    }
}

// ---------------------------------------------------------------------------
// Bucketed adjacency build: slot = atomicAdd(counts[dst]); bucket or overflow.
// ---------------------------------------------------------------------------
__global__ void build_kernel(const int* __restrict__ src, const int* __restrict__ dst,
                             int* __restrict__ counts, int* __restrict__ bucket,
                             int* __restrict__ ovf_cnt, int* __restrict__ ovf_dst,
                             int* __restrict__ ovf_src, int E)
{
    int i0 = (blockIdx.x * blockDim.x + threadIdx.x) * 4;
    #pragma unroll
    for (int j = 0; j < 4; ++j) {
        int i = i0 + j;
        if (i < E) {
            int d = dst[i], s = src[i];
            int slot = atomicAdd(&counts[d], 1);
            if (slot < CAP) {
                bucket[(size_t)d * CAP + slot] = s;
            } else {
                int o = atomicAdd(ovf_cnt, 1);
                ovf_dst[o] = d;
                ovf_src[o] = s;
            }
        }
    }
}

// ---------------------------------------------------------------------------
// Attention aggregation: one wave per destination node, 4-edge unroll.
// blob per node (768B): fp8 k [0,256) | bf16 v [256,768).
// ---------------------------------------------------------------------------
__global__ __launch_bounds__(256) void attn_kernel(
    const ushort* __restrict__ qb, const uchar* __restrict__ blob,
    const int* __restrict__ counts, const int* __restrict__ bucket,
    const int* __restrict__ ovf_cnt, const int* __restrict__ ovf_dst,
    const int* __restrict__ ovf_src,
    float* __restrict__ out, int n)
{
    int node = (int)((blockIdx.x * (size_t)blockDim.x + threadIdx.x) >> 6);
    if (node >= n) return;
    const int lane = threadIdx.x & 63;
    const int j0   = lane * 4;

    ushort4 qu = *(const ushort4*)&qb[(size_t)node * D_TOT + j0];
    float q0 = bf2f(qu.x), q1 = bf2f(qu.y), q2 = bf2f(qu.z), q3 = bf2f(qu.w);

    float acc0 = 0.f, acc1 = 0.f, acc2 = 0.f, acc3 = 0.f, z = 0.f;

    const int deg  = counts[node];
    const int pend = (deg < CAP) ? deg : CAP;
    const int* bkt = &bucket[(size_t)node * CAP];

    int p = 0;
    for (; p + 4 <= pend; p += 4) {
        int s0 = bkt[p], s1 = bkt[p + 1], s2 = bkt[p + 2], s3 = bkt[p + 3];
        const uchar* b0 = blob + (size_t)s0 * 768;
        const uchar* b1 = blob + (size_t)s1 * 768;
        const uchar* b2 = blob + (size_t)s2 * 768;
        const uchar* b3 = blob + (size_t)s3 * 768;
        uint kw0 = *(const uint*)(b0 + j0);
        uint kw1 = *(const uint*)(b1 + j0);
        uint kw2 = *(const uint*)(b2 + j0);
        uint kw3 = *(const uint*)(b3 + j0);
        ushort4 v0u = *(const ushort4*)(b0 + 256 + j0 * 2);
        ushort4 v1u = *(const ushort4*)(b1 + 256 + j0 * 2);
        ushort4 v2u = *(const ushort4*)(b2 + 256 + j0 * 2);
        ushort4 v3u = *(const ushort4*)(b3 + 256 + j0 * 2);

        f32x2 a0 = __builtin_amdgcn_cvt_pk_f32_fp8(kw0, false);
        f32x2 c0 = __builtin_amdgcn_cvt_pk_f32_fp8(kw0, true);
        f32x2 a1 = __builtin_amdgcn_cvt_pk_f32_fp8(kw1, false);
        f32x2 c1 = __builtin_amdgcn_cvt_pk_f32_fp8(kw1, true);
        f32x2 a2 = __builtin_amdgcn_cvt_pk_f32_fp8(kw2, false);
        f32x2 c2 = __builtin_amdgcn_cvt_pk_f32_fp8(kw2, true);
        f32x2 a3 = __builtin_amdgcn_cvt_pk_f32_fp8(kw3, false);
        f32x2 c3 = __builtin_amdgcn_cvt_pk_f32_fp8(kw3, true);

        float d0 = a0[0] * q0 + a0[1] * q1 + c0[0] * q2 + c0[1] * q3;
        float d1 = a1[0] * q0 + a1[1] * q1 + c1[0] * q2 + c1[1] * q3;
        float d2 = a2[0] * q0 + a2[1] * q1 + c2[0] * q2 + c2[1] * q3;
        float d3 = a3[0] * q0 + a3[1] * q1 + c3[0] * q2 + c3[1] * q3;
        d0 += __shfl_xor(d0, 1); d1 += __shfl_xor(d1, 1); d2 += __shfl_xor(d2, 1); d3 += __shfl_xor(d3, 1);
        d0 += __shfl_xor(d0, 2); d1 += __shfl_xor(d1, 2); d2 += __shfl_xor(d2, 2); d3 += __shfl_xor(d3, 2);
        d0 += __shfl_xor(d0, 4); d1 += __shfl_xor(d1, 4); d2 += __shfl_xor(d2, 4); d3 += __shfl_xor(d3, 4);
        float sc0 = __expf(d0 * SCALE);
        float sc1 = __expf(d1 * SCALE);
        float sc2 = __expf(d2 * SCALE);
        float sc3 = __expf(d3 * SCALE);
        acc0 += sc0 * bf2f(v0u.x) + sc1 * bf2f(v1u.x) + sc2 * bf2f(v2u.x) + sc3 * bf2f(v3u.x);
        acc1 += sc0 * bf2f(v0u.y) + sc1 * bf2f(v1u.y) + sc2 * bf2f(v2u.y) + sc3 * bf2f(v3u.y);
        acc2 += sc0 * bf2f(v0u.z) + sc1 * bf2f(v1u.z) + sc2 * bf2f(v2u.z) + sc3 * bf2f(v3u.z);
        acc3 += sc0 * bf2f(v0u.w) + sc1 * bf2f(v1u.w) + sc2 * bf2f(v2u.w) + sc3 * bf2f(v3u.w);
        z += sc0 + sc1 + sc2 + sc3;
    }
    for (; p < pend; ++p) {
        int s = bkt[p];
        const uchar* b = blob + (size_t)s * 768;
        uint kw = *(const uint*)(b + j0);
        ushort4 vu = *(const ushort4*)(b + 256 + j0 * 2);
        f32x2 a = __builtin_amdgcn_cvt_pk_f32_fp8(kw, false);
        f32x2 c = __builtin_amdgcn_cvt_pk_f32_fp8(kw, true);
        float d = a[0] * q0 + a[1] * q1 + c[0] * q2 + c[1] * q3;
        d += __shfl_xor(d, 1);
        d += __shfl_xor(d, 2);
        d += __shfl_xor(d, 4);
        float sc = __expf(d * SCALE);
        acc0 += sc * bf2f(vu.x);
        acc1 += sc * bf2f(vu.y);
        acc2 += sc * bf2f(vu.z);
        acc3 += sc * bf2f(vu.w);
        z += sc;
    }

    // Overflow edges (never taken for this distribution; correctness net)
    int ovf_n = *ovf_cnt;
    for (int i = 0; i < ovf_n; ++i) {
        if (ovf_dst[i] == node) {
            int s = ovf_src[i];
            const uchar* b = blob + (size_t)s * 768;
            uint kw = *(const uint*)(b + j0);
            ushort4 vu = *(const ushort4*)(b + 256 + j0 * 2);
            f32x2 a = __builtin_amdgcn_cvt_pk_f32_fp8(kw, false);
            f32x2 c = __builtin_amdgcn_cvt_pk_f32_fp8(kw, true);
            float d = a[0] * q0 + a[1] * q1 + c[0] * q2 + c[1] * q3;
            d += __shfl_xor(d, 1);
            d += __shfl_xor(d, 2);
            d += __shfl_xor(d, 4);
            float sc = __expf(d * SCALE);
            acc0 += sc * bf2f(vu.x);
            acc1 += sc * bf2f(vu.y);
            acc2 += sc * bf2f(vu.z);
            acc3 += sc * bf2f(vu.w);
            z += sc;
        }
    }

    float inv = 1.0f / (z + EPS);
    f32x4 o;
    o[0] = acc0 * inv; o[1] = acc1 * inv; o[2] = acc2 * inv; o[3] = acc3 * inv;
    __builtin_nontemporal_store(o, (f32x4*)&out[(size_t)node * D_TOT + j0]);
}

// ---------------------------------------------------------------------------
extern "C" void kernel_launch(void* const* d_in, const int* in_sizes, int n_in,
                              void* d_out, int out_size, void* d_ws, size_t ws_size,
                              hipStream_t stream)
{
    const float* h   = (const float*)d_in[0];
    const int*   src = (const int*)  d_in[1];
    const int*   dst = (const int*)  d_in[2];
    const float* Wq  = (const float*)d_in[3];
    const float* bq  = (const float*)d_in[4];
    const float* Wk  = (const float*)d_in[5];
    const float* bk  = (const float*)d_in[6];
    const float* Wv  = (const float*)d_in[7];
    const float* bv  = (const float*)d_in[8];
    float* out = (float*)d_out;

    const int N = in_sizes[0] / IN_DIM;
    const int E = in_sizes[1];

    // Workspace: qb bf16[N][256] (25.6MB) | blob[N][768B] (38.4MB) | WT x3 |
    //            bucket[N][CAP] int (25.6MB) | counts[N]+ovf_cnt | ovf x2 (E each)
    ushort* qb   = (ushort*)d_ws;
    uchar*  blob = (uchar*)(qb + (size_t)N * D_TOT);
    ushort* WqT  = (ushort*)(blob + (size_t)N * 768);
    ushort* WkT  = WqT + D_TOT * IN_DIM;
    ushort* WvT  = WkT + D_TOT * IN_DIM;
    int* bucket  = (int*)(WvT + D_TOT * IN_DIM);
    int* counts  = bucket + (size_t)N * CAP;
    int* ovf_cnt = counts + N;
    int* ovf_dst = ovf_cnt + 8;          // keep alignment
    int* ovf_src = ovf_dst + E;

    // 1) W -> bf16 transposed
    conv_w_kernel<<<(3 * IN_DIM * D_TOT + 255) / 256, 256, 0, stream>>>(
        Wq, Wk, Wv, WqT, WkT, WvT);

    // 2) QKV projection: single pass over h, z-loop inside block
    qkv_gemm_mfma<<<(N + 63) / 64, 256, 0, stream>>>(
        h, WqT, bq, WkT, bk, WvT, bv, qb, blob, N);

    // 3) Bucketed adjacency (counts + ovf_cnt zeroed in one memset)
    (void)hipMemsetAsync(counts, 0, ((size_t)N + 8) * sizeof(int), stream);
    {
        int eblocks = (E / 4 + 255) / 256;
        build_kernel<<<eblocks, 256, 0, stream>>>(src, dst, counts, bucket,
                                                  ovf_cnt, ovf_dst, ovf_src, E);
    }
    // 4) Per-node attention aggregation (1 wave per node)
    attn_kernel<<<(N + 3) / 4, 256, 0, stream>>>(qb, blob, counts, bucket,
                                                 ovf_cnt, ovf_dst, ovf_src, out, N);
}

// Round 7
// 336.463 us; speedup vs baseline: 2.8023x; 1.0311x over previous
//
#include <hip/hip_runtime.h>
#include <hip/hip_bf16.h>

#define IN_DIM   256
#define NUM_HEAD 8
#define OUT_DIM  32
#define D_TOT    256
#define SCALE    0.17677669529663687f   // 1/sqrt(32)
#define EPS      1e-9f
#define CAP      128                    // bucket capacity per node (17 sigma)

typedef __attribute__((ext_vector_type(4))) float f32x4;
typedef __attribute__((ext_vector_type(2))) float f32x2;
typedef __attribute__((ext_vector_type(8))) short short8;

__device__ inline ushort f2bf(float f) {
    uint u = __float_as_uint(f);
    uint r = (u + 0x7FFF + ((u >> 16) & 1)) >> 16;   // round-to-nearest-even
    return (ushort)r;
}
__device__ inline float bf2f(ushort u) {
    return __uint_as_float(((uint)u) << 16);
}
__device__ inline uchar f2fp8(float f) {
    int p = __builtin_amdgcn_cvt_pk_fp8_f32(f, f, 0, false);
    return (uchar)(p & 0xff);
}

// ---------------------------------------------------------------------------
// W pack: fp32 W[k][n] -> bf16 MFMA-fragment order
//   Bp[z][k0s(8)][ct(16)][lane(64)][j(8)]  (= 384 KB total)
// where frag element j of lane l (l15=l&15, l4=l>>4) for col-tile ct at
// k-step k0s is W[k0s*32 + l4*8 + j][ct*16 + l15].
// One thread writes one 16B fragment slice (8 bf16).
// ---------------------------------------------------------------------------
__global__ void conv_w_kernel(const float* __restrict__ Wq, const float* __restrict__ Wk,
                              const float* __restrict__ Wv, ushort* __restrict__ Bp)
{
    int i = blockIdx.x * blockDim.x + threadIdx.x;   // 0 .. 3*8192-1
    if (i >= 3 * 8192) return;
    int z    = i >> 13;
    int rem  = i & 8191;
    int k0s  = rem >> 10;
    int rem2 = rem & 1023;
    int ct   = rem2 >> 6;
    int lane = rem2 & 63;
    int l15 = lane & 15, l4 = lane >> 4;
    int col = ct * 16 + l15;
    const float* W = (z == 0) ? Wq : (z == 1) ? Wk : Wv;

    ushort o[8];
    #pragma unroll
    for (int j = 0; j < 8; ++j)
        o[j] = f2bf(W[(size_t)(k0s * 32 + l4 * 8 + j) * D_TOT + col]);
    *(uint4*)&Bp[(size_t)i * 8] = *(uint4*)o;
}

// ---------------------------------------------------------------------------
// QKV GEMM, bf16 MFMA 16x16x32. BM=64 rows/block, 256 thr = 4 waves.
// A (bf16, full K=256) staged in LDS ONCE from fp32 h (single barrier).
// B fragments loaded DIRECTLY from packed Bp (coalesced 1KB/wave, L2-hot).
// Wave w owns cols [w*64, w*64+64). No barriers in the K-loop.
// Epilogue: q -> bf16 qb[N][256]; k -> fp8 blob[row][0..255];
//           v -> bf16 blob[row][256..767].
// ---------------------------------------------------------------------------
__global__ __launch_bounds__(256) void qkv_gemm_mfma(
    const float* __restrict__ h, const ushort* __restrict__ Bp,
    const float* __restrict__ bq, const float* __restrict__ bk,
    const float* __restrict__ bv,
    ushort* __restrict__ qb, uchar* __restrict__ blob,
    int M)
{
    __shared__ ushort A_lds[64][264];   // full-K rows, pad 256->264

    const int tid  = threadIdx.x;
    const int m0   = blockIdx.x * 64;
    const int lane = tid & 63;
    const int wid  = tid >> 6;        // 0..3 -> col panel of 64
    const int l15  = lane & 15;
    const int l4   = lane >> 4;

    // Stage A once: thread t covers row r=t>>2, k-quarter qd=t&3 (64 k elems)
    {
        int r   = tid >> 2;
        int qd  = tid & 3;
        int row = m0 + r;
        #pragma unroll
        for (int i = 0; i < 8; ++i) {
            int k = qd * 64 + i * 8;
            float4 f0 = make_float4(0.f, 0.f, 0.f, 0.f), f1 = f0;
            if (row < M) {
                const float* src = &h[(size_t)row * IN_DIM + k];
                f0 = *(const float4*)src;
                f1 = *(const float4*)(src + 4);
            }
            uint4 val;
            val.x = (uint)f2bf(f0.x) | ((uint)f2bf(f0.y) << 16);
            val.y = (uint)f2bf(f0.z) | ((uint)f2bf(f0.w) << 16);
            val.z = (uint)f2bf(f1.x) | ((uint)f2bf(f1.y) << 16);
            val.w = (uint)f2bf(f1.z) | ((uint)f2bf(f1.w) << 16);
            *(uint4*)&A_lds[r][k] = val;
        }
    }
    __syncthreads();

    #pragma unroll
    for (int z = 0; z < 3; ++z) {
        const float* bias = (z == 0) ? bq : (z == 1) ? bk : bv;
        const ushort* Bz  = Bp + (size_t)z * 65536;

        f32x4 acc[4][4] = {};   // [mi rows][ni cols]

        #pragma unroll
        for (int k0s = 0; k0s < 8; ++k0s) {
            short8 afr[4], bfr[4];
            #pragma unroll
            for (int mi = 0; mi < 4; ++mi)
                afr[mi] = *(const short8*)&A_lds[mi * 16 + l15][k0s * 32 + l4 * 8];
            #pragma unroll
            for (int ni = 0; ni < 4; ++ni)
                bfr[ni] = *(const short8*)&Bz[(size_t)(((k0s * 16) + (wid * 4 + ni)) * 64 + lane) * 8];
            #pragma unroll
            for (int mi = 0; mi < 4; ++mi)
                #pragma unroll
                for (int ni = 0; ni < 4; ++ni)
                    acc[mi][ni] = __builtin_amdgcn_mfma_f32_16x16x32_bf16(
                        afr[mi], bfr[ni], acc[mi][ni], 0, 0, 0);
        }

        float bias_c[4];
        #pragma unroll
        for (int ni = 0; ni < 4; ++ni)
            bias_c[ni] = bias[wid * 64 + ni * 16 + l15];

        #pragma unroll
        for (int mi = 0; mi < 4; ++mi) {
            #pragma unroll
            for (int r = 0; r < 4; ++r) {
                int row_g = m0 + mi * 16 + l4 * 4 + r;
                if (row_g < M) {
                    #pragma unroll
                    for (int ni = 0; ni < 4; ++ni) {
                        int   col_g = wid * 64 + ni * 16 + l15;
                        float val   = acc[mi][ni][r] + bias_c[ni];
                        if (z == 0) {
                            qb[(size_t)row_g * 256 + col_g] = f2bf(val);
                        } else if (z == 1) {
                            blob[(size_t)row_g * 768 + col_g] = f2fp8(val);
                        } else {
                            *(ushort*)(blob + (size_t)row_g * 768 + 256 + col_g * 2) = f2bf(val);
                        }
                    }
                }
            }
        }
    }
}

// ---------------------------------------------------------------------------
// Bucketed adjacency build: slot = atomicAdd(counts[dst]); bucket or overflow.
// ---------------------------------------------------------------------------
__global__ void build_kernel(const int* __restrict__ src, const int* __restrict__ dst,
                             int* __restrict__ counts, int* __restrict__ bucket,
                             int* __restrict__ ovf_cnt, int* __restrict__ ovf_dst,
                             int* __restrict__ ovf_src, int E)
{
    int i0 = (blockIdx.x * blockDim.x + threadIdx.x) * 4;
    #pragma unroll
    for (int j = 0; j < 4; ++j) {
        int i = i0 + j;
        if (i < E) {
            int d = dst[i], s = src[i];
            int slot = atomicAdd(&counts[d], 1);
            if (slot < CAP) {
                bucket[(size_t)d * CAP + slot] = s;
            } else {
                int o = atomicAdd(ovf_cnt, 1);
                ovf_dst[o] = d;
                ovf_src[o] = s;
            }
        }
    }
}

// ---------------------------------------------------------------------------
// Attention aggregation: one wave per destination node, 4-edge unroll.
// blob per node (768B): fp8 k [0,256) | bf16 v [256,768).
// ---------------------------------------------------------------------------
__global__ __launch_bounds__(256) void attn_kernel(
    const ushort* __restrict__ qb, const uchar* __restrict__ blob,
    const int* __restrict__ counts, const int* __restrict__ bucket,
    const int* __restrict__ ovf_cnt, const int* __restrict__ ovf_dst,
    const int* __restrict__ ovf_src,
    float* __restrict__ out, int n)
{
    int node = (int)((blockIdx.x * (size_t)blockDim.x + threadIdx.x) >> 6);
    if (node >= n) return;
    const int lane = threadIdx.x & 63;
    const int j0   = lane * 4;

    ushort4 qu = *(const ushort4*)&qb[(size_t)node * D_TOT + j0];
    float q0 = bf2f(qu.x), q1 = bf2f(qu.y), q2 = bf2f(qu.z), q3 = bf2f(qu.w);

    float acc0 = 0.f, acc1 = 0.f, acc2 = 0.f, acc3 = 0.f, z = 0.f;

    const int deg  = counts[node];
    const int pend = (deg < CAP) ? deg : CAP;
    const int* bkt = &bucket[(size_t)node * CAP];

    int p = 0;
    for (; p + 4 <= pend; p += 4) {
        int s0 = bkt[p], s1 = bkt[p + 1], s2 = bkt[p + 2], s3 = bkt[p + 3];
        const uchar* b0 = blob + (size_t)s0 * 768;
        const uchar* b1 = blob + (size_t)s1 * 768;
        const uchar* b2 = blob + (size_t)s2 * 768;
        const uchar* b3 = blob + (size_t)s3 * 768;
        uint kw0 = *(const uint*)(b0 + j0);
        uint kw1 = *(const uint*)(b1 + j0);
        uint kw2 = *(const uint*)(b2 + j0);
        uint kw3 = *(const uint*)(b3 + j0);
        ushort4 v0u = *(const ushort4*)(b0 + 256 + j0 * 2);
        ushort4 v1u = *(const ushort4*)(b1 + 256 + j0 * 2);
        ushort4 v2u = *(const ushort4*)(b2 + 256 + j0 * 2);
        ushort4 v3u = *(const ushort4*)(b3 + 256 + j0 * 2);

        f32x2 a0 = __builtin_amdgcn_cvt_pk_f32_fp8(kw0, false);
        f32x2 c0 = __builtin_amdgcn_cvt_pk_f32_fp8(kw0, true);
        f32x2 a1 = __builtin_amdgcn_cvt_pk_f32_fp8(kw1, false);
        f32x2 c1 = __builtin_amdgcn_cvt_pk_f32_fp8(kw1, true);
        f32x2 a2 = __builtin_amdgcn_cvt_pk_f32_fp8(kw2, false);
        f32x2 c2 = __builtin_amdgcn_cvt_pk_f32_fp8(kw2, true);
        f32x2 a3 = __builtin_amdgcn_cvt_pk_f32_fp8(kw3, false);
        f32x2 c3 = __builtin_amdgcn_cvt_pk_f32_fp8(kw3, true);

        float d0 = a0[0] * q0 + a0[1] * q1 + c0[0] * q2 + c0[1] * q3;
        float d1 = a1[0] * q0 + a1[1] * q1 + c1[0] * q2 + c1[1] * q3;
        float d2 = a2[0] * q0 + a2[1] * q1 + c2[0] * q2 + c2[1] * q3;
        float d3 = a3[0] * q0 + a3[1] * q1 + c3[0] * q2 + c3[1] * q3;
        d0 += __shfl_xor(d0, 1); d1 += __shfl_xor(d1, 1); d2 += __shfl_xor(d2, 1); d3 += __shfl_xor(d3, 1);
        d0 += __shfl_xor(d0, 2); d1 += __shfl_xor(d1, 2); d2 += __shfl_xor(d2, 2); d3 += __shfl_xor(d3, 2);
        d0 += __shfl_xor(d0, 4); d1 += __shfl_xor(d1, 4); d2 += __shfl_xor(d2, 4); d3 += __shfl_xor(d3, 4);
        float sc0 = __expf(d0 * SCALE);
        float sc1 = __expf(d1 * SCALE);
        float sc2 = __expf(d2 * SCALE);
        float sc3 = __expf(d3 * SCALE);
        acc0 += sc0 * bf2f(v0u.x) + sc1 * bf2f(v1u.x) + sc2 * bf2f(v2u.x) + sc3 * bf2f(v3u.x);
        acc1 += sc0 * bf2f(v0u.y) + sc1 * bf2f(v1u.y) + sc2 * bf2f(v2u.y) + sc3 * bf2f(v3u.y);
        acc2 += sc0 * bf2f(v0u.z) + sc1 * bf2f(v1u.z) + sc2 * bf2f(v2u.z) + sc3 * bf2f(v3u.z);
        acc3 += sc0 * bf2f(v0u.w) + sc1 * bf2f(v1u.w) + sc2 * bf2f(v2u.w) + sc3 * bf2f(v3u.w);
        z += sc0 + sc1 + sc2 + sc3;
    }
    for (; p < pend; ++p) {
        int s = bkt[p];
        const uchar* b = blob + (size_t)s * 768;
        uint kw = *(const uint*)(b + j0);
        ushort4 vu = *(const ushort4*)(b + 256 + j0 * 2);
        f32x2 a = __builtin_amdgcn_cvt_pk_f32_fp8(kw, false);
        f32x2 c = __builtin_amdgcn_cvt_pk_f32_fp8(kw, true);
        float d = a[0] * q0 + a[1] * q1 + c[0] * q2 + c[1] * q3;
        d += __shfl_xor(d, 1);
        d += __shfl_xor(d, 2);
        d += __shfl_xor(d, 4);
        float sc = __expf(d * SCALE);
        acc0 += sc * bf2f(vu.x);
        acc1 += sc * bf2f(vu.y);
        acc2 += sc * bf2f(vu.z);
        acc3 += sc * bf2f(vu.w);
        z += sc;
    }

    // Overflow edges (never taken for this distribution; correctness net)
    int ovf_n = *ovf_cnt;
    for (int i = 0; i < ovf_n; ++i) {
        if (ovf_dst[i] == node) {
            int s = ovf_src[i];
            const uchar* b = blob + (size_t)s * 768;
            uint kw = *(const uint*)(b + j0);
            ushort4 vu = *(const ushort4*)(b + 256 + j0 * 2);
            f32x2 a = __builtin_amdgcn_cvt_pk_f32_fp8(kw, false);
            f32x2 c = __builtin_amdgcn_cvt_pk_f32_fp8(kw, true);
            float d = a[0] * q0 + a[1] * q1 + c[0] * q2 + c[1] * q3;
            d += __shfl_xor(d, 1);
            d += __shfl_xor(d, 2);
            d += __shfl_xor(d, 4);
            float sc = __expf(d * SCALE);
            acc0 += sc * bf2f(vu.x);
            acc1 += sc * bf2f(vu.y);
            acc2 += sc * bf2f(vu.z);
            acc3 += sc * bf2f(vu.w);
            z += sc;
        }
    }

    float inv = 1.0f / (z + EPS);
    f32x4 o;
    o[0] = acc0 * inv; o[1] = acc1 * inv; o[2] = acc2 * inv; o[3] = acc3 * inv;
    __builtin_nontemporal_store(o, (f32x4*)&out[(size_t)node * D_TOT + j0]);
}

// ---------------------------------------------------------------------------
extern "C" void kernel_launch(void* const* d_in, const int* in_sizes, int n_in,
                              void* d_out, int out_size, void* d_ws, size_t ws_size,
                              hipStream_t stream)
{
    const float* h   = (const float*)d_in[0];
    const int*   src = (const int*)  d_in[1];
    const int*   dst = (const int*)  d_in[2];
    const float* Wq  = (const float*)d_in[3];
    const float* bq  = (const float*)d_in[4];
    const float* Wk  = (const float*)d_in[5];
    const float* bk  = (const float*)d_in[6];
    const float* Wv  = (const float*)d_in[7];
    const float* bv  = (const float*)d_in[8];
    float* out = (float*)d_out;

    const int N = in_sizes[0] / IN_DIM;
    const int E = in_sizes[1];

    // Workspace: qb bf16[N][256] (25.6MB) | blob[N][768B] (38.4MB) |
    //            Bp (3x65536 bf16, 384KB) | bucket[N][CAP] int (25.6MB) |
    //            counts[N]+ovf_cnt | ovf x2 (E each)
    ushort* qb   = (ushort*)d_ws;
    uchar*  blob = (uchar*)(qb + (size_t)N * D_TOT);
    ushort* Bp   = (ushort*)(blob + (size_t)N * 768);
    int* bucket  = (int*)(Bp + 3 * 65536);
    int* counts  = bucket + (size_t)N * CAP;
    int* ovf_cnt = counts + N;
    int* ovf_dst = ovf_cnt + 8;          // keep alignment
    int* ovf_src = ovf_dst + E;

    // 1) W -> packed bf16 MFMA-fragment layout
    conv_w_kernel<<<(3 * 8192 + 255) / 256, 256, 0, stream>>>(Wq, Wk, Wv, Bp);

    // 2) QKV projection: single pass over h, z-loop inside block, no B staging
    qkv_gemm_mfma<<<(N + 63) / 64, 256, 0, stream>>>(
        h, Bp, bq, bk, bv, qb, blob, N);

    // 3) Bucketed adjacency (counts + ovf_cnt zeroed in one memset)
    (void)hipMemsetAsync(counts, 0, ((size_t)N + 8) * sizeof(int), stream);
    {
        int eblocks = (E / 4 + 255) / 256;
        build_kernel<<<eblocks, 256, 0, stream>>>(src, dst, counts, bucket,
                                                  ovf_cnt, ovf_dst, ovf_src, E);
    }
    // 4) Per-node attention aggregation (1 wave per node)
    attn_kernel<<<(N + 3) / 4, 256, 0, stream>>>(qb, blob, counts, bucket,
                                                 ovf_cnt, ovf_dst, ovf_src, out, N);
}

// Round 8
// 265.040 us; speedup vs baseline: 3.5575x; 1.2695x over previous
//
#include <hip/hip_runtime.h>
#include <hip/hip_bf16.h>

#define IN_DIM   256
#define NUM_HEAD 8
#define OUT_DIM  32
#define D_TOT    256
#define SCALE    0.17677669529663687f   // 1/sqrt(32)
#define EPS      1e-9f
#define CAP      64                     // bucket capacity (Poisson(32): P(>64)~1e-7)

typedef __attribute__((ext_vector_type(4))) float f32x4;
typedef __attribute__((ext_vector_type(2))) float f32x2;
typedef __attribute__((ext_vector_type(8))) short short8;

__device__ inline ushort f2bf(float f) {
    uint u = __float_as_uint(f);
    uint r = (u + 0x7FFF + ((u >> 16) & 1)) >> 16;   // round-to-nearest-even
    return (ushort)r;
}
__device__ inline float bf2f(ushort u) {
    return __uint_as_float(((uint)u) << 16);
}
__device__ inline uchar f2fp8(float f) {
    int p = __builtin_amdgcn_cvt_pk_fp8_f32(f, f, 0, false);
    return (uchar)(p & 0xff);
}

// ---------------------------------------------------------------------------
// W pack: fp32 W[k][n] -> bf16 MFMA-fragment order
//   Bp[z][k0s(8)][ct(16)][lane(64)][j(8)]  (= 384 KB total)
// ---------------------------------------------------------------------------
__global__ void conv_w_kernel(const float* __restrict__ Wq, const float* __restrict__ Wk,
                              const float* __restrict__ Wv, ushort* __restrict__ Bp)
{
    int i = blockIdx.x * blockDim.x + threadIdx.x;   // 0 .. 3*8192-1
    if (i >= 3 * 8192) return;
    int z    = i >> 13;
    int rem  = i & 8191;
    int k0s  = rem >> 10;
    int rem2 = rem & 1023;
    int ct   = rem2 >> 6;
    int lane = rem2 & 63;
    int l15 = lane & 15, l4 = lane >> 4;
    int col = ct * 16 + l15;
    const float* W = (z == 0) ? Wq : (z == 1) ? Wk : Wv;

    ushort o[8];
    #pragma unroll
    for (int j = 0; j < 8; ++j)
        o[j] = f2bf(W[(size_t)(k0s * 32 + l4 * 8 + j) * D_TOT + col]);
    *(uint4*)&Bp[(size_t)i * 8] = *(uint4*)o;
}

// ---------------------------------------------------------------------------
// FUSED: role-striped blocks.
//   idx%3==0 (idx<3*gb): GEMM block  (gemm_id = idx/3, 64 rows)
//   else               : build block (1024 edges each)
// GEMM: A (full K) staged in LDS once; B fragments direct from packed Bp
// (L2-hot); no K-loop barriers. Epilogue: q->bf16 qb; k->fp8 blob[0..255];
// v->bf16 blob[256..767].
// Build: slot = atomicAdd(counts[dst]); bucket or overflow.
// ---------------------------------------------------------------------------
__global__ __launch_bounds__(256) void fused_gemm_build(
    const float* __restrict__ h, const ushort* __restrict__ Bp,
    const float* __restrict__ bq, const float* __restrict__ bk,
    const float* __restrict__ bv,
    ushort* __restrict__ qb, uchar* __restrict__ blob, int M,
    const int* __restrict__ src, const int* __restrict__ dst,
    int* __restrict__ counts, int* __restrict__ bucket,
    int* __restrict__ ovf_cnt, int* __restrict__ ovf_dst,
    int* __restrict__ ovf_src, int E, int gb)
{
    __shared__ ushort A_lds[64][264];   // full-K rows, pad 256->264

    const int idx = blockIdx.x;
    const int tid = threadIdx.x;

    if (idx < 3 * gb && (idx % 3) == 0) {
        // ------------------------- GEMM role -------------------------
        const int m0   = (idx / 3) * 64;
        const int lane = tid & 63;
        const int wid  = tid >> 6;
        const int l15  = lane & 15;
        const int l4   = lane >> 4;

        {   // Stage A once
            int r   = tid >> 2;
            int qd  = tid & 3;
            int row = m0 + r;
            #pragma unroll
            for (int i = 0; i < 8; ++i) {
                int k = qd * 64 + i * 8;
                float4 f0 = make_float4(0.f, 0.f, 0.f, 0.f), f1 = f0;
                if (row < M) {
                    const float* srcp = &h[(size_t)row * IN_DIM + k];
                    f0 = *(const float4*)srcp;
                    f1 = *(const float4*)(srcp + 4);
                }
                uint4 val;
                val.x = (uint)f2bf(f0.x) | ((uint)f2bf(f0.y) << 16);
                val.y = (uint)f2bf(f0.z) | ((uint)f2bf(f0.w) << 16);
                val.z = (uint)f2bf(f1.x) | ((uint)f2bf(f1.y) << 16);
                val.w = (uint)f2bf(f1.z) | ((uint)f2bf(f1.w) << 16);
                *(uint4*)&A_lds[r][k] = val;
            }
        }
        __syncthreads();

        #pragma unroll
        for (int z = 0; z < 3; ++z) {
            const float* bias = (z == 0) ? bq : (z == 1) ? bk : bv;
            const ushort* Bz  = Bp + (size_t)z * 65536;

            f32x4 acc[4][4] = {};

            #pragma unroll
            for (int k0s = 0; k0s < 8; ++k0s) {
                short8 afr[4], bfr[4];
                #pragma unroll
                for (int mi = 0; mi < 4; ++mi)
                    afr[mi] = *(const short8*)&A_lds[mi * 16 + l15][k0s * 32 + l4 * 8];
                #pragma unroll
                for (int ni = 0; ni < 4; ++ni)
                    bfr[ni] = *(const short8*)&Bz[(size_t)(((k0s * 16) + (wid * 4 + ni)) * 64 + lane) * 8];
                #pragma unroll
                for (int mi = 0; mi < 4; ++mi)
                    #pragma unroll
                    for (int ni = 0; ni < 4; ++ni)
                        acc[mi][ni] = __builtin_amdgcn_mfma_f32_16x16x32_bf16(
                            afr[mi], bfr[ni], acc[mi][ni], 0, 0, 0);
            }

            float bias_c[4];
            #pragma unroll
            for (int ni = 0; ni < 4; ++ni)
                bias_c[ni] = bias[wid * 64 + ni * 16 + l15];

            #pragma unroll
            for (int mi = 0; mi < 4; ++mi) {
                #pragma unroll
                for (int r = 0; r < 4; ++r) {
                    int row_g = m0 + mi * 16 + l4 * 4 + r;
                    if (row_g < M) {
                        #pragma unroll
                        for (int ni = 0; ni < 4; ++ni) {
                            int   col_g = wid * 64 + ni * 16 + l15;
                            float val   = acc[mi][ni][r] + bias_c[ni];
                            if (z == 0) {
                                qb[(size_t)row_g * 256 + col_g] = f2bf(val);
                            } else if (z == 1) {
                                blob[(size_t)row_g * 768 + col_g] = f2fp8(val);
                            } else {
                                *(ushort*)(blob + (size_t)row_g * 768 + 256 + col_g * 2) = f2bf(val);
                            }
                        }
                    }
                }
            }
        }
    } else {
        // ------------------------- build role -------------------------
        int build_id = (idx < 3 * gb) ? (idx / 3) * 2 + (idx % 3) - 1
                                      : 2 * gb + (idx - 3 * gb);
        int i0 = (build_id * 256 + tid) * 4;
        #pragma unroll
        for (int j = 0; j < 4; ++j) {
            int i = i0 + j;
            if (i < E) {
                int d = dst[i], s = src[i];
                int slot = atomicAdd(&counts[d], 1);
                if (slot < CAP) {
                    bucket[(size_t)d * CAP + slot] = s;
                } else {
                    int o = atomicAdd(ovf_cnt, 1);
                    ovf_dst[o] = d;
                    ovf_src[o] = s;
                }
            }
        }
    }
}

// ---------------------------------------------------------------------------
// Attention aggregation: one wave per destination node, 4-edge unroll.
// blob per node (768B): fp8 k [0,256) | bf16 v [256,768).
// ---------------------------------------------------------------------------
__global__ __launch_bounds__(256) void attn_kernel(
    const ushort* __restrict__ qb, const uchar* __restrict__ blob,
    const int* __restrict__ counts, const int* __restrict__ bucket,
    const int* __restrict__ ovf_cnt, const int* __restrict__ ovf_dst,
    const int* __restrict__ ovf_src,
    float* __restrict__ out, int n)
{
    int node = (int)((blockIdx.x * (size_t)blockDim.x + threadIdx.x) >> 6);
    if (node >= n) return;
    const int lane = threadIdx.x & 63;
    const int j0   = lane * 4;

    ushort4 qu = *(const ushort4*)&qb[(size_t)node * D_TOT + j0];
    float q0 = bf2f(qu.x), q1 = bf2f(qu.y), q2 = bf2f(qu.z), q3 = bf2f(qu.w);

    float acc0 = 0.f, acc1 = 0.f, acc2 = 0.f, acc3 = 0.f, z = 0.f;

    const int deg  = counts[node];
    const int pend = (deg < CAP) ? deg : CAP;
    const int* bkt = &bucket[(size_t)node * CAP];

    int p = 0;
    for (; p + 4 <= pend; p += 4) {
        int s0 = bkt[p], s1 = bkt[p + 1], s2 = bkt[p + 2], s3 = bkt[p + 3];
        const uchar* b0 = blob + (size_t)s0 * 768;
        const uchar* b1 = blob + (size_t)s1 * 768;
        const uchar* b2 = blob + (size_t)s2 * 768;
        const uchar* b3 = blob + (size_t)s3 * 768;
        uint kw0 = *(const uint*)(b0 + j0);
        uint kw1 = *(const uint*)(b1 + j0);
        uint kw2 = *(const uint*)(b2 + j0);
        uint kw3 = *(const uint*)(b3 + j0);
        ushort4 v0u = *(const ushort4*)(b0 + 256 + j0 * 2);
        ushort4 v1u = *(const ushort4*)(b1 + 256 + j0 * 2);
        ushort4 v2u = *(const ushort4*)(b2 + 256 + j0 * 2);
        ushort4 v3u = *(const ushort4*)(b3 + 256 + j0 * 2);

        f32x2 a0 = __builtin_amdgcn_cvt_pk_f32_fp8(kw0, false);
        f32x2 c0 = __builtin_amdgcn_cvt_pk_f32_fp8(kw0, true);
        f32x2 a1 = __builtin_amdgcn_cvt_pk_f32_fp8(kw1, false);
        f32x2 c1 = __builtin_amdgcn_cvt_pk_f32_fp8(kw1, true);
        f32x2 a2 = __builtin_amdgcn_cvt_pk_f32_fp8(kw2, false);
        f32x2 c2 = __builtin_amdgcn_cvt_pk_f32_fp8(kw2, true);
        f32x2 a3 = __builtin_amdgcn_cvt_pk_f32_fp8(kw3, false);
        f32x2 c3 = __builtin_amdgcn_cvt_pk_f32_fp8(kw3, true);

        float d0 = a0[0] * q0 + a0[1] * q1 + c0[0] * q2 + c0[1] * q3;
        float d1 = a1[0] * q0 + a1[1] * q1 + c1[0] * q2 + c1[1] * q3;
        float d2 = a2[0] * q0 + a2[1] * q1 + c2[0] * q2 + c2[1] * q3;
        float d3 = a3[0] * q0 + a3[1] * q1 + c3[0] * q2 + c3[1] * q3;
        d0 += __shfl_xor(d0, 1); d1 += __shfl_xor(d1, 1); d2 += __shfl_xor(d2, 1); d3 += __shfl_xor(d3, 1);
        d0 += __shfl_xor(d0, 2); d1 += __shfl_xor(d1, 2); d2 += __shfl_xor(d2, 2); d3 += __shfl_xor(d3, 2);
        d0 += __shfl_xor(d0, 4); d1 += __shfl_xor(d1, 4); d2 += __shfl_xor(d2, 4); d3 += __shfl_xor(d3, 4);
        float sc0 = __expf(d0 * SCALE);
        float sc1 = __expf(d1 * SCALE);
        float sc2 = __expf(d2 * SCALE);
        float sc3 = __expf(d3 * SCALE);
        acc0 += sc0 * bf2f(v0u.x) + sc1 * bf2f(v1u.x) + sc2 * bf2f(v2u.x) + sc3 * bf2f(v3u.x);
        acc1 += sc0 * bf2f(v0u.y) + sc1 * bf2f(v1u.y) + sc2 * bf2f(v2u.y) + sc3 * bf2f(v3u.y);
        acc2 += sc0 * bf2f(v0u.z) + sc1 * bf2f(v1u.z) + sc2 * bf2f(v2u.z) + sc3 * bf2f(v3u.z);
        acc3 += sc0 * bf2f(v0u.w) + sc1 * bf2f(v1u.w) + sc2 * bf2f(v2u.w) + sc3 * bf2f(v3u.w);
        z += sc0 + sc1 + sc2 + sc3;
    }
    for (; p < pend; ++p) {
        int s = bkt[p];
        const uchar* b = blob + (size_t)s * 768;
        uint kw = *(const uint*)(b + j0);
        ushort4 vu = *(const ushort4*)(b + 256 + j0 * 2);
        f32x2 a = __builtin_amdgcn_cvt_pk_f32_fp8(kw, false);
        f32x2 c = __builtin_amdgcn_cvt_pk_f32_fp8(kw, true);
        float d = a[0] * q0 + a[1] * q1 + c[0] * q2 + c[1] * q3;
        d += __shfl_xor(d, 1);
        d += __shfl_xor(d, 2);
        d += __shfl_xor(d, 4);
        float sc = __expf(d * SCALE);
        acc0 += sc * bf2f(vu.x);
        acc1 += sc * bf2f(vu.y);
        acc2 += sc * bf2f(vu.z);
        acc3 += sc * bf2f(vu.w);
        z += sc;
    }

    // Overflow edges (essentially never populated; correctness net)
    int ovf_n = *ovf_cnt;
    for (int i = 0; i < ovf_n; ++i) {
        if (ovf_dst[i] == node) {
            int s = ovf_src[i];
            const uchar* b = blob + (size_t)s * 768;
            uint kw = *(const uint*)(b + j0);
            ushort4 vu = *(const ushort4*)(b + 256 + j0 * 2);
            f32x2 a = __builtin_amdgcn_cvt_pk_f32_fp8(kw, false);
            f32x2 c = __builtin_amdgcn_cvt_pk_f32_fp8(kw, true);
            float d = a[0] * q0 + a[1] * q1 + c[0] * q2 + c[1] * q3;
            d += __shfl_xor(d, 1);
            d += __shfl_xor(d, 2);
            d += __shfl_xor(d, 4);
            float sc = __expf(d * SCALE);
            acc0 += sc * bf2f(vu.x);
            acc1 += sc * bf2f(vu.y);
            acc2 += sc * bf2f(vu.z);
            acc3 += sc * bf2f(vu.w);
            z += sc;
        }
    }

    float inv = 1.0f / (z + EPS);
    f32x4 o;
    o[0] = acc0 * inv; o[1] = acc1 * inv; o[2] = acc2 * inv; o[3] = acc3 * inv;
    __builtin_nontemporal_store(o, (f32x4*)&out[(size_t)node * D_TOT + j0]);
}

// ---------------------------------------------------------------------------
extern "C" void kernel_launch(void* const* d_in, const int* in_sizes, int n_in,
                              void* d_out, int out_size, void* d_ws, size_t ws_size,
                              hipStream_t stream)
{
    const float* h   = (const float*)d_in[0];
    const int*   src = (const int*)  d_in[1];
    const int*   dst = (const int*)  d_in[2];
    const float* Wq  = (const float*)d_in[3];
    const float* bq  = (const float*)d_in[4];
    const float* Wk  = (const float*)d_in[5];
    const float* bk  = (const float*)d_in[6];
    const float* Wv  = (const float*)d_in[7];
    const float* bv  = (const float*)d_in[8];
    float* out = (float*)d_out;

    const int N = in_sizes[0] / IN_DIM;
    const int E = in_sizes[1];

    // Workspace: qb bf16[N][256] (25.6MB) | blob[N][768B] (38.4MB) |
    //            Bp (384KB) | bucket[N][CAP] int (12.8MB) |
    //            counts[N]+ovf_cnt | ovf x2 (E each)
    ushort* qb   = (ushort*)d_ws;
    uchar*  blob = (uchar*)(qb + (size_t)N * D_TOT);
    ushort* Bp   = (ushort*)(blob + (size_t)N * 768);
    int* bucket  = (int*)(Bp + 3 * 65536);
    int* counts  = bucket + (size_t)N * CAP;
    int* ovf_cnt = counts + N;
    int* ovf_dst = ovf_cnt + 8;          // keep alignment
    int* ovf_src = ovf_dst + E;

    // 0) zero counts + ovf_cnt (build depends on it; issued first)
    (void)hipMemsetAsync(counts, 0, ((size_t)N + 8) * sizeof(int), stream);

    // 1) W -> packed bf16 MFMA-fragment layout (GEMM blocks read it)
    conv_w_kernel<<<(3 * 8192 + 255) / 256, 256, 0, stream>>>(Wq, Wk, Wv, Bp);

    // 2) FUSED gemm + build (role-striped blocks)
    {
        const int gb = (N + 63) / 64;
        const int bb_needed = (E + 1023) / 1024;
        const int extra = (bb_needed > 2 * gb) ? (bb_needed - 2 * gb) : 0;
        const int T = 3 * gb + extra;
        fused_gemm_build<<<T, 256, 0, stream>>>(
            h, Bp, bq, bk, bv, qb, blob, N,
            src, dst, counts, bucket, ovf_cnt, ovf_dst, ovf_src, E, gb);
    }

    // 3) Per-node attention aggregation (1 wave per node)
    attn_kernel<<<(N + 3) / 4, 256, 0, stream>>>(qb, blob, counts, bucket,
                                                 ovf_cnt, ovf_dst, ovf_src, out, N);
}